// Round 1
// baseline (721.336 us; speedup 1.0000x reference)
//
#include <hip/hip_runtime.h>
#include <math.h>

// Problem constants (shapes fixed by the reference)
#define FD 128          // feature dim F == hidden dim H
#define GATES 4

__device__ __forceinline__ float sigmoidf_(float v) {
    return 1.0f / (1.0f + expf(-v));
}

// ---- Kernel 1: degree accumulation: deg[src[e]] += ew[e] ----
__global__ void k_edge_deg(const float* __restrict__ ew, const int* __restrict__ src,
                           float* __restrict__ deg, int E) {
    int e = blockIdx.x * blockDim.x + threadIdx.x;
    if (e < E) atomicAdd(&deg[src[e]], ew[e]);
}

// ---- Kernel 2: dis[n] = deg>0 ? rsqrt(max(deg,1e-12)) : 0  (in place) ----
__global__ void k_node_dis(float* __restrict__ deg, int n) {
    int i = blockIdx.x * blockDim.x + threadIdx.x;
    if (i < n) {
        float d = deg[i];
        deg[i] = (d > 0.0f) ? rsqrtf(fmaxf(d, 1e-12f)) : 0.0f;
    }
}

// ---- Kernel 3: edge scatter: Tx1{x,h}[dst] += -w_sym * {x,h}[src] ----
// 128 threads per edge (feature-parallel), 2 edges per 256-thread block, grid-stride.
__global__ void k_edge_scatter(const float* __restrict__ x, const float* __restrict__ h,
                               const float* __restrict__ ew,
                               const int* __restrict__ src, const int* __restrict__ dst,
                               const float* __restrict__ dis,
                               float* __restrict__ tx, float* __restrict__ th, int E) {
    int j    = threadIdx.x & (FD - 1);
    int half = threadIdx.x >> 7;
    for (int e = blockIdx.x * 2 + half; e < E; e += gridDim.x * 2) {
        int s = src[e], d = dst[e];
        float w = -dis[s] * ew[e] * dis[d];
        atomicAdd(&tx[d * FD + j], w * x[s * FD + j]);
        atomicAdd(&th[d * FD + j], w * h[s * FD + j]);
    }
}

// ---- Kernel 4: fused gates GEMM ----
// gates(N x 512) = [x | Tx1x | h | Tx1h] (N x 512) @ Wcat (512 x 512)
// Wcat[k][g*128+j]: k in [0,128)->Wx[g][0][k][j]; [128,256)->Wx[g][1][k-128][j];
//                   [256,384)->Wh[g][0][k-256][j]; [384,512)->Wh[g][1][k-384][j]
#define BM 64
#define BN 64
#define BK 32
__global__ __launch_bounds__(256) void k_gemm_gates(
    const float* __restrict__ x,  const float* __restrict__ tx,
    const float* __restrict__ h,  const float* __restrict__ th,
    const float* __restrict__ Wx, const float* __restrict__ Wh,
    float* __restrict__ gates, int n) {

    __shared__ float As[BK][BM + 1];   // transposed A tile: As[k][m]
    __shared__ float Bs[BK][BN];

    const int tid  = threadIdx.x;
    const int row0 = blockIdx.x * BM;
    const int cb   = blockIdx.y;          // 0..7
    const int g    = cb >> 1;             // gate
    const int j0   = (cb & 1) * 64;       // col offset within gate

    const int tm = (tid / 16) * 4;
    const int tn = (tid % 16) * 4;

    float acc[4][4] = {};

    for (int kt = 0; kt < 16; ++kt) {
        const int sel  = kt >> 2;            // which source matrix
        const int koff = (kt & 3) * BK;      // k offset within that matrix (0..96)

        const float* Aptr = (sel == 0) ? x : (sel == 1) ? tx : (sel == 2) ? h : th;
        const float* Wb   = (sel < 2) ? Wx : Wh;
        // W row base for (g, cheb-order sel&1): element [kk][j] at Wb[wbase + kk*128 + j]
        const int wbase = ((g * 2 + (sel & 1)) * FD) * FD + j0;

        __syncthreads();
        // Load A tile (64 rows x 32 k), 2 passes, float4 each
        #pragma unroll
        for (int p = 0; p < 2; ++p) {
            int r  = p * 32 + (tid >> 3);
            int k4 = (tid & 7) * 4;
            int gr = row0 + r;
            float4 v = make_float4(0.f, 0.f, 0.f, 0.f);
            if (gr < n) v = *reinterpret_cast<const float4*>(&Aptr[gr * FD + koff + k4]);
            As[k4 + 0][r] = v.x;
            As[k4 + 1][r] = v.y;
            As[k4 + 2][r] = v.z;
            As[k4 + 3][r] = v.w;
        }
        // Load B tile (32 k x 64 cols), 2 passes, float4 each
        #pragma unroll
        for (int p = 0; p < 2; ++p) {
            int kr = p * 16 + (tid >> 4);
            int c4 = (tid & 15) * 4;
            float4 v = *reinterpret_cast<const float4*>(&Wb[wbase + (koff + kr) * FD + c4]);
            *reinterpret_cast<float4*>(&Bs[kr][c4]) = v;
        }
        __syncthreads();

        #pragma unroll
        for (int kk = 0; kk < BK; ++kk) {
            float a[4], bv[4];
            #pragma unroll
            for (int i = 0; i < 4; ++i) a[i]  = As[kk][tm + i];
            #pragma unroll
            for (int i = 0; i < 4; ++i) bv[i] = Bs[kk][tn + i];
            #pragma unroll
            for (int i = 0; i < 4; ++i)
                #pragma unroll
                for (int jj = 0; jj < 4; ++jj)
                    acc[i][jj] = fmaf(a[i], bv[jj], acc[i][jj]);
        }
    }

    #pragma unroll
    for (int i = 0; i < 4; ++i) {
        int gr = row0 + tm + i;
        if (gr < n) {
            #pragma unroll
            for (int jj = 0; jj < 4; ++jj)
                gates[gr * (GATES * FD) + g * FD + j0 + tn + jj] = acc[i][jj];
        }
    }
}

// ---- Kernel 5: LSTM gate combine + write outputs ----
__global__ void k_combine(const float* __restrict__ gates, const float* __restrict__ c,
                          const float* __restrict__ b, const float* __restrict__ wc,
                          float* __restrict__ out, int n) {
    int idx = blockIdx.x * blockDim.x + threadIdx.x;
    if (idx >= n * FD) return;
    int nr = idx >> 7, j = idx & (FD - 1);
    const float* grow = gates + nr * (GATES * FD);
    float cv = c[idx];

    float gi = grow[0 * FD + j] + wc[0 * FD + j] * cv + b[0 * FD + j];
    float gf = grow[1 * FD + j] + wc[1 * FD + j] * cv + b[1 * FD + j];
    float gg = grow[2 * FD + j] + b[2 * FD + j];

    float iv = sigmoidf_(gi);
    float fv = sigmoidf_(gf);
    float cn = fv * cv + iv * tanhf(gg);

    float go = grow[3 * FD + j] + wc[2 * FD + j] * cn + b[3 * FD + j];
    float ov = sigmoidf_(go);
    float hn = ov * tanhf(cn);

    int NH = n * FD;
    out[idx]          = hn;   // output 0: h_new
    out[NH + idx]     = hn;   // output 1: h_new
    out[2 * NH + idx] = cn;   // output 2: c_new
}

extern "C" void kernel_launch(void* const* d_in, const int* in_sizes, int n_in,
                              void* d_out, int out_size, void* d_ws, size_t ws_size,
                              hipStream_t stream) {
    const float* x   = (const float*)d_in[0];
    const float* ew  = (const float*)d_in[1];
    const float* h   = (const float*)d_in[2];
    const float* c   = (const float*)d_in[3];
    const float* Wx  = (const float*)d_in[4];
    const float* Wh  = (const float*)d_in[5];
    const float* b   = (const float*)d_in[6];
    const float* wc  = (const float*)d_in[7];
    const int*   src = (const int*)d_in[8];
    const int*   dst = (const int*)d_in[9];

    const int n = in_sizes[0] / FD;   // 20000
    const int E = in_sizes[1];        // 640000

    float* ws    = (float*)d_ws;
    float* deg   = ws;                      // n floats (becomes dis in place)
    float* tx    = deg + n;                 // n*128
    float* th    = tx + (size_t)n * FD;     // n*128
    float* gates = th + (size_t)n * FD;     // n*512

    // zero deg + tx + th (contiguous)
    hipMemsetAsync(deg, 0, (size_t)(n + 2 * n * FD) * sizeof(float), stream);

    k_edge_deg<<<(E + 255) / 256, 256, 0, stream>>>(ew, src, deg, E);
    k_node_dis<<<(n + 255) / 256, 256, 0, stream>>>(deg, n);
    k_edge_scatter<<<40000, 256, 0, stream>>>(x, h, ew, src, dst, deg, tx, th, E);

    dim3 ggrid((n + BM - 1) / BM, (GATES * FD) / BN);
    k_gemm_gates<<<ggrid, 256, 0, stream>>>(x, tx, h, th, Wx, Wh, gates, n);

    k_combine<<<(n * FD + 255) / 256, 256, 0, stream>>>(gates, c, b, wc, (float*)d_out, n);
}

// Round 2
// 377.895 us; speedup vs baseline: 1.9088x; 1.9088x over previous
//
#include <hip/hip_runtime.h>
#include <math.h>

#define FD 128
#define GATES 4

__device__ __forceinline__ float sigmoidf_(float v) {
    return 1.0f / (1.0f + expf(-v));
}

// ---- Kernel 1: histogram: deg[src] += ew (float), cnt[dst] += 1 (int) ----
__global__ void k_hist(const float* __restrict__ ew, const int* __restrict__ src,
                       const int* __restrict__ dst, float* __restrict__ deg,
                       int* __restrict__ cnt, int E) {
    int e = blockIdx.x * blockDim.x + threadIdx.x;
    if (e < E) {
        atomicAdd(&deg[src[e]], ew[e]);
        atomicAdd(&cnt[dst[e]], 1);
    }
}

// ---- Kernel 2: dis[n] = deg>0 ? rsqrt(max(deg,1e-12)) : 0  (in place) ----
__global__ void k_node_dis(float* __restrict__ deg, int n) {
    int i = blockIdx.x * blockDim.x + threadIdx.x;
    if (i < n) {
        float d = deg[i];
        deg[i] = (d > 0.0f) ? rsqrtf(fmaxf(d, 1e-12f)) : 0.0f;
    }
}

// ---- Kernel 3: exclusive scan of cnt -> off (single block, 1024 threads) ----
__global__ __launch_bounds__(1024) void k_scan(const int* __restrict__ cnt,
                                               int* __restrict__ off, int n) {
    __shared__ int warp_sums[16];
    __shared__ int base_sh;
    if (threadIdx.x == 0) base_sh = 0;
    __syncthreads();

    const int lane = threadIdx.x & 63;
    const int wid  = threadIdx.x >> 6;

    for (int start = 0; start < n; start += 1024) {
        int i = start + (int)threadIdx.x;
        int v = (i < n) ? cnt[i] : 0;
        // inclusive scan within wave
        int s = v;
        #pragma unroll
        for (int d = 1; d < 64; d <<= 1) {
            int t = __shfl_up(s, d);
            if (lane >= d) s += t;
        }
        if (lane == 63) warp_sums[wid] = s;
        __syncthreads();
        if (wid == 0 && lane < 16) {
            int ws = warp_sums[lane];
            #pragma unroll
            for (int d = 1; d < 16; d <<= 1) {
                int t = __shfl_up(ws, d);
                if (lane >= d) ws += t;
            }
            warp_sums[lane] = ws;
        }
        __syncthreads();
        int wbase = (wid > 0) ? warp_sums[wid - 1] : 0;
        int excl  = base_sh + wbase + (s - v);
        if (i < n) off[i] = excl;
        int chunk_total = warp_sums[15];
        __syncthreads();                 // everyone has read base_sh & warp_sums
        if (threadIdx.x == 0) base_sh += chunk_total;
        __syncthreads();
    }
    if (threadIdx.x == 0) off[n] = base_sh;
}

// ---- Kernel 4: bucket fill: CSR-ordered (src, w_sym) per dst ----
__global__ void k_fill(const float* __restrict__ ew, const int* __restrict__ src,
                       const int* __restrict__ dst, const float* __restrict__ dis,
                       int* __restrict__ cur, int* __restrict__ esrc,
                       float* __restrict__ ewgt, int E) {
    int e = blockIdx.x * blockDim.x + threadIdx.x;
    if (e >= E) return;
    int s = src[e], d = dst[e];
    float w = -dis[s] * ew[e] * dis[d];
    int p = atomicAdd(&cur[d], 1);
    esrc[p] = s;
    ewgt[p] = w;
}

// ---- Kernel 5: gather: tx[d] = sum_e w*x[src], th[d] = sum_e w*h[src] ----
// 128 threads per node (feature-parallel), 2 nodes per 256-thread block.
__global__ __launch_bounds__(256) void k_gather(
    const float* __restrict__ x, const float* __restrict__ h,
    const int* __restrict__ off, const int* __restrict__ esrc,
    const float* __restrict__ ewgt,
    float* __restrict__ tx, float* __restrict__ th, int n) {

    int d = blockIdx.x * 2 + (threadIdx.x >> 7);
    int j = threadIdx.x & (FD - 1);
    if (d >= n) return;

    int p0 = off[d], p1 = off[d + 1];
    float ax = 0.f, ah = 0.f;
    int p = p0;
    for (; p + 1 < p1; p += 2) {
        int   s0 = esrc[p],  s1 = esrc[p + 1];
        float w0 = ewgt[p],  w1 = ewgt[p + 1];
        float x0 = x[s0 * FD + j], x1 = x[s1 * FD + j];
        float h0 = h[s0 * FD + j], h1 = h[s1 * FD + j];
        ax = fmaf(w0, x0, ax); ah = fmaf(w0, h0, ah);
        ax = fmaf(w1, x1, ax); ah = fmaf(w1, h1, ah);
    }
    if (p < p1) {
        int s = esrc[p]; float w = ewgt[p];
        ax = fmaf(w, x[s * FD + j], ax);
        ah = fmaf(w, h[s * FD + j], ah);
    }
    tx[d * FD + j] = ax;
    th[d * FD + j] = ah;
}

// ---- Kernel 6: fused gates GEMM ----
// gates(N x 512) = [x | Tx1x | h | Tx1h] (N x 512) @ Wcat (512 x 512)
#define BM 64
#define BN 64
#define BK 32
__global__ __launch_bounds__(256) void k_gemm_gates(
    const float* __restrict__ x,  const float* __restrict__ tx,
    const float* __restrict__ h,  const float* __restrict__ th,
    const float* __restrict__ Wx, const float* __restrict__ Wh,
    float* __restrict__ gates, int n) {

    __shared__ float As[BK][BM + 1];
    __shared__ float Bs[BK][BN];

    const int tid  = threadIdx.x;
    const int row0 = blockIdx.x * BM;
    const int cb   = blockIdx.y;          // 0..7
    const int g    = cb >> 1;
    const int j0   = (cb & 1) * 64;

    const int tm = (tid / 16) * 4;
    const int tn = (tid % 16) * 4;

    float acc[4][4] = {};

    for (int kt = 0; kt < 16; ++kt) {
        const int sel  = kt >> 2;
        const int koff = (kt & 3) * BK;

        const float* Aptr = (sel == 0) ? x : (sel == 1) ? tx : (sel == 2) ? h : th;
        const float* Wb   = (sel < 2) ? Wx : Wh;
        const int wbase = ((g * 2 + (sel & 1)) * FD) * FD + j0;

        __syncthreads();
        #pragma unroll
        for (int p = 0; p < 2; ++p) {
            int r  = p * 32 + (tid >> 3);
            int k4 = (tid & 7) * 4;
            int gr = row0 + r;
            float4 v = make_float4(0.f, 0.f, 0.f, 0.f);
            if (gr < n) v = *reinterpret_cast<const float4*>(&Aptr[gr * FD + koff + k4]);
            As[k4 + 0][r] = v.x;
            As[k4 + 1][r] = v.y;
            As[k4 + 2][r] = v.z;
            As[k4 + 3][r] = v.w;
        }
        #pragma unroll
        for (int p = 0; p < 2; ++p) {
            int kr = p * 16 + (tid >> 4);
            int c4 = (tid & 15) * 4;
            float4 v = *reinterpret_cast<const float4*>(&Wb[wbase + (koff + kr) * FD + c4]);
            *reinterpret_cast<float4*>(&Bs[kr][c4]) = v;
        }
        __syncthreads();

        #pragma unroll
        for (int kk = 0; kk < BK; ++kk) {
            float a[4], bv[4];
            #pragma unroll
            for (int i = 0; i < 4; ++i) a[i]  = As[kk][tm + i];
            #pragma unroll
            for (int i = 0; i < 4; ++i) bv[i] = Bs[kk][tn + i];
            #pragma unroll
            for (int i = 0; i < 4; ++i)
                #pragma unroll
                for (int jj = 0; jj < 4; ++jj)
                    acc[i][jj] = fmaf(a[i], bv[jj], acc[i][jj]);
        }
    }

    #pragma unroll
    for (int i = 0; i < 4; ++i) {
        int gr = row0 + tm + i;
        if (gr < n) {
            #pragma unroll
            for (int jj = 0; jj < 4; ++jj)
                gates[gr * (GATES * FD) + g * FD + j0 + tn + jj] = acc[i][jj];
        }
    }
}

// ---- Kernel 7: LSTM gate combine + write outputs ----
__global__ void k_combine(const float* __restrict__ gates, const float* __restrict__ c,
                          const float* __restrict__ b, const float* __restrict__ wc,
                          float* __restrict__ out, int n) {
    int idx = blockIdx.x * blockDim.x + threadIdx.x;
    if (idx >= n * FD) return;
    int nr = idx >> 7, j = idx & (FD - 1);
    const float* grow = gates + nr * (GATES * FD);
    float cv = c[idx];

    float gi = grow[0 * FD + j] + wc[0 * FD + j] * cv + b[0 * FD + j];
    float gf = grow[1 * FD + j] + wc[1 * FD + j] * cv + b[1 * FD + j];
    float gg = grow[2 * FD + j] + b[2 * FD + j];

    float iv = sigmoidf_(gi);
    float fv = sigmoidf_(gf);
    float cn = fv * cv + iv * tanhf(gg);

    float go = grow[3 * FD + j] + wc[2 * FD + j] * cn + b[3 * FD + j];
    float ov = sigmoidf_(go);
    float hn = ov * tanhf(cn);

    int NH = n * FD;
    out[idx]          = hn;
    out[NH + idx]     = hn;
    out[2 * NH + idx] = cn;
}

extern "C" void kernel_launch(void* const* d_in, const int* in_sizes, int n_in,
                              void* d_out, int out_size, void* d_ws, size_t ws_size,
                              hipStream_t stream) {
    const float* x   = (const float*)d_in[0];
    const float* ew  = (const float*)d_in[1];
    const float* h   = (const float*)d_in[2];
    const float* c   = (const float*)d_in[3];
    const float* Wx  = (const float*)d_in[4];
    const float* Wh  = (const float*)d_in[5];
    const float* b   = (const float*)d_in[6];
    const float* wc  = (const float*)d_in[7];
    const int*   src = (const int*)d_in[8];
    const int*   dst = (const int*)d_in[9];

    const int n = in_sizes[0] / FD;   // 20000
    const int E = in_sizes[1];        // 640000

    // workspace layout (all 4-byte elements)
    float* deg  = (float*)d_ws;                 // n
    int*   cnt  = (int*)(deg + n);              // n
    int*   off  = cnt + n;                      // n+1
    int*   cur  = off + n + 1;                  // n
    int*   esrc = cur + n;                      // E
    float* ewgt = (float*)(esrc + E);           // E
    float* tx   = ewgt + E;                     // n*FD
    float* th   = tx + (size_t)n * FD;          // n*FD
    float* gates= th + (size_t)n * FD;          // n*4*FD

    // zero deg (n floats) + cnt (n ints), contiguous
    hipMemsetAsync(deg, 0, (size_t)(2 * n) * sizeof(float), stream);

    k_hist<<<(E + 255) / 256, 256, 0, stream>>>(ew, src, dst, deg, cnt, E);
    k_node_dis<<<(n + 255) / 256, 256, 0, stream>>>(deg, n);
    k_scan<<<1, 1024, 0, stream>>>(cnt, off, n);
    hipMemcpyAsync(cur, off, (size_t)n * sizeof(int), hipMemcpyDeviceToDevice, stream);
    k_fill<<<(E + 255) / 256, 256, 0, stream>>>(ew, src, dst, deg, cur, esrc, ewgt, E);
    k_gather<<<(n + 1) / 2, 256, 0, stream>>>(x, h, off, esrc, ewgt, tx, th, n);

    dim3 ggrid((n + BM - 1) / BM, (GATES * FD) / BN);
    k_gemm_gates<<<ggrid, 256, 0, stream>>>(x, tx, h, th, Wx, Wh, gates, n);

    k_combine<<<(n * FD + 255) / 256, 256, 0, stream>>>(gates, c, b, wc, (float*)d_out, n);
}

// Round 3
// 267.794 us; speedup vs baseline: 2.6936x; 1.4111x over previous
//
#include <hip/hip_runtime.h>
#include <math.h>

#define FD 128
#define GATES 4

typedef __attribute__((ext_vector_type(8))) short bf16x8;
typedef __attribute__((ext_vector_type(4))) float f32x4;

__device__ __forceinline__ float sigmoidf_(float v) {
    return 1.0f / (1.0f + expf(-v));
}

__device__ __forceinline__ unsigned short f2bf(float f) {
    unsigned int u = __builtin_bit_cast(unsigned int, f);
    u += 0x7fffu + ((u >> 16) & 1u);           // RNE (finite values)
    return (unsigned short)(u >> 16);
}

__device__ __forceinline__ float bf2f(unsigned short s) {
    unsigned int u = ((unsigned int)s) << 16;
    return __builtin_bit_cast(float, u);
}

// ---- Kernel 1: histogram: deg[src] += ew (float), cnt[dst] += 1 (int) ----
__global__ void k_hist(const float* __restrict__ ew, const int* __restrict__ src,
                       const int* __restrict__ dst, float* __restrict__ deg,
                       int* __restrict__ cnt, int E) {
    int e = blockIdx.x * blockDim.x + threadIdx.x;
    if (e < E) {
        atomicAdd(&deg[src[e]], ew[e]);
        atomicAdd(&cnt[dst[e]], 1);
    }
}

// ---- Kernel 2: dis = deg>0 ? rsqrt(max(deg,1e-12)) : 0  (in place) ----
__global__ void k_node_dis(float* __restrict__ deg, int n) {
    int i = blockIdx.x * blockDim.x + threadIdx.x;
    if (i < n) {
        float d = deg[i];
        deg[i] = (d > 0.0f) ? rsqrtf(fmaxf(d, 1e-12f)) : 0.0f;
    }
}

// ---- Kernel 3: exclusive scan of cnt -> off (single block) ----
__global__ __launch_bounds__(1024) void k_scan(const int* __restrict__ cnt,
                                               int* __restrict__ off, int n) {
    __shared__ int warp_sums[16];
    __shared__ int base_sh;
    if (threadIdx.x == 0) base_sh = 0;
    __syncthreads();

    const int lane = threadIdx.x & 63;
    const int wid  = threadIdx.x >> 6;

    for (int start = 0; start < n; start += 1024) {
        int i = start + (int)threadIdx.x;
        int v = (i < n) ? cnt[i] : 0;
        int s = v;
        #pragma unroll
        for (int d = 1; d < 64; d <<= 1) {
            int t = __shfl_up(s, d);
            if (lane >= d) s += t;
        }
        if (lane == 63) warp_sums[wid] = s;
        __syncthreads();
        if (wid == 0 && lane < 16) {
            int ws = warp_sums[lane];
            #pragma unroll
            for (int d = 1; d < 16; d <<= 1) {
                int t = __shfl_up(ws, d);
                if (lane >= d) ws += t;
            }
            warp_sums[lane] = ws;
        }
        __syncthreads();
        int wbase = (wid > 0) ? warp_sums[wid - 1] : 0;
        int excl  = base_sh + wbase + (s - v);
        if (i < n) off[i] = excl;
        int chunk_total = warp_sums[15];
        __syncthreads();
        if (threadIdx.x == 0) base_sh += chunk_total;
        __syncthreads();
    }
    if (threadIdx.x == 0) off[n] = base_sh;
}

// ---- Kernel 4: bucket fill: CSR-ordered (src, w_sym) per dst ----
__global__ void k_fill(const float* __restrict__ ew, const int* __restrict__ src,
                       const int* __restrict__ dst, const float* __restrict__ dis,
                       int* __restrict__ cur, int* __restrict__ esrc,
                       float* __restrict__ ewgt, int E) {
    int e = blockIdx.x * blockDim.x + threadIdx.x;
    if (e >= E) return;
    int s = src[e], d = dst[e];
    float w = -dis[s] * ew[e] * dis[d];
    int p = atomicAdd(&cur[d], 1);
    esrc[p] = s;
    ewgt[p] = w;
}

// ---- Kernel 5: gather: tx[d] = sum w*x[src], th[d] = sum w*h[src] ----
__global__ __launch_bounds__(256) void k_gather(
    const float* __restrict__ x, const float* __restrict__ h,
    const int* __restrict__ off, const int* __restrict__ esrc,
    const float* __restrict__ ewgt,
    float* __restrict__ tx, float* __restrict__ th, int n) {

    int d = blockIdx.x * 2 + (threadIdx.x >> 7);
    int j = threadIdx.x & (FD - 1);
    if (d >= n) return;

    int p0 = off[d], p1 = off[d + 1];
    float ax = 0.f, ah = 0.f;
    int p = p0;
    for (; p + 1 < p1; p += 2) {
        int   s0 = esrc[p],  s1 = esrc[p + 1];
        float w0 = ewgt[p],  w1 = ewgt[p + 1];
        float x0 = x[s0 * FD + j], x1 = x[s1 * FD + j];
        float h0 = h[s0 * FD + j], h1 = h[s1 * FD + j];
        ax = fmaf(w0, x0, ax); ah = fmaf(w0, h0, ah);
        ax = fmaf(w1, x1, ax); ah = fmaf(w1, h1, ah);
    }
    if (p < p1) {
        int s = esrc[p]; float w = ewgt[p];
        ax = fmaf(w, x[s * FD + j], ax);
        ah = fmaf(w, h[s * FD + j], ah);
    }
    tx[d * FD + j] = ax;
    th[d * FD + j] = ah;
}

// ---- Kernel 6: pack A = [x|tx|h|th] into MFMA-fragment-ordered bf16 ----
// Fragment (rb, kb): 16 rows x 32 k. Within: lane = (r&15) + 16*((k&31)>>3),
// byte i holds k = kb*32 + (lane>>4)*8 + i. Fragment id = rb*16 + kb.
__global__ __launch_bounds__(256) void k_pack_a(
    const float* __restrict__ x,  const float* __restrict__ tx,
    const float* __restrict__ h,  const float* __restrict__ th,
    unsigned short* __restrict__ Abf, int n, int nfrag) {

    int frag = blockIdx.x * 4 + (threadIdx.x >> 6);
    if (frag >= nfrag) return;
    int lane = threadIdx.x & 63;
    int rb = frag >> 4, kb = frag & 15;
    int r  = rb * 16 + (lane & 15);
    int k0 = kb * 32 + (lane >> 4) * 8;

    const float* srcp = (kb < 4) ? x : (kb < 8) ? tx : (kb < 12) ? h : th;
    int col = k0 & (FD - 1);

    unsigned short outv[8];
    if (r < n) {
        const float* p = srcp + (size_t)r * FD + col;
        float4 v0 = *reinterpret_cast<const float4*>(p);
        float4 v1 = *reinterpret_cast<const float4*>(p + 4);
        outv[0] = f2bf(v0.x); outv[1] = f2bf(v0.y);
        outv[2] = f2bf(v0.z); outv[3] = f2bf(v0.w);
        outv[4] = f2bf(v1.x); outv[5] = f2bf(v1.y);
        outv[6] = f2bf(v1.z); outv[7] = f2bf(v1.w);
    } else {
        #pragma unroll
        for (int i = 0; i < 8; ++i) outv[i] = 0;
    }
    *reinterpret_cast<uint4*>(Abf + (size_t)frag * 512 + lane * 8) =
        *reinterpret_cast<uint4*>(outv);
}

// ---- Kernel 7: pack Wcat (512x512) into B-fragment-ordered bf16 ----
// Fragment (cb, kb): 32 k x 16 cols. lane = (col&15) + 16*((k&31)>>3),
// byte i: k = kb*32 + (lane>>4)*8 + i. Fragment id = cb*16 + kb.
__global__ void k_pack_w(const float* __restrict__ Wx, const float* __restrict__ Wh,
                         unsigned short* __restrict__ Wbf) {
    int frag = blockIdx.x * 4 + (threadIdx.x >> 6);   // 0..511
    int lane = threadIdx.x & 63;
    int cb = frag >> 4, kb = frag & 15;
    int col = cb * 16 + (lane & 15);
    int k0  = kb * 32 + (lane >> 4) * 8;

    int sel  = k0 >> 7;                // 0..3 : Wx0, Wx1, Wh0, Wh1
    int g    = col >> 7;
    int j    = col & (FD - 1);
    const float* Wb = (sel < 2) ? Wx : Wh;
    const float* p = Wb + (((size_t)g * 2 + (sel & 1)) * FD + (k0 & (FD - 1))) * FD + j;

    unsigned short outv[8];
    #pragma unroll
    for (int i = 0; i < 8; ++i) outv[i] = f2bf(p[(size_t)i * FD]);

    *reinterpret_cast<uint4*>(Wbf + (size_t)frag * 512 + lane * 8) =
        *reinterpret_cast<uint4*>(outv);
}

// ---- Kernel 8: MFMA GEMM: gates(bf16, N x 512) = Abf @ Wbf ----
// No LDS: fragments loaded coalesced from fragment-ordered buffers.
// Each wave: 64x64 output tile. 4 waves/block.
__global__ __launch_bounds__(256) void k_gemm_mfma(
    const unsigned short* __restrict__ Abf, const unsigned short* __restrict__ Wbf,
    unsigned short* __restrict__ gates, int n) {

    int wg   = blockIdx.x * 4 + (threadIdx.x >> 6);
    int lane = threadIdx.x & 63;
    int rt = wg >> 3;          // 0..312  (row tile, 64 rows)
    int ct = wg & 7;           // 0..7    (col tile, 64 cols)

    f32x4 acc[4][4];
    #pragma unroll
    for (int mi = 0; mi < 4; ++mi)
        #pragma unroll
        for (int nj = 0; nj < 4; ++nj)
            acc[mi][nj] = (f32x4)0.0f;

    const size_t aoff = ((size_t)(rt * 4) * 16) * 512 + lane * 8;
    const size_t boff = ((size_t)(ct * 4) * 16) * 512 + lane * 8;

    for (int kb = 0; kb < 16; ++kb) {
        bf16x8 a[4], b[4];
        #pragma unroll
        for (int mi = 0; mi < 4; ++mi)
            a[mi] = *reinterpret_cast<const bf16x8*>(Abf + aoff + (size_t)(mi * 16 + kb) * 512);
        #pragma unroll
        for (int nj = 0; nj < 4; ++nj)
            b[nj] = *reinterpret_cast<const bf16x8*>(Wbf + boff + (size_t)(nj * 16 + kb) * 512);
        #pragma unroll
        for (int mi = 0; mi < 4; ++mi)
            #pragma unroll
            for (int nj = 0; nj < 4; ++nj)
                acc[mi][nj] = __builtin_amdgcn_mfma_f32_16x16x32_bf16(
                                  a[mi], b[nj], acc[mi][nj], 0, 0, 0);
    }

    const int r0 = rt * 64, c0 = ct * 64;
    #pragma unroll
    for (int mi = 0; mi < 4; ++mi) {
        #pragma unroll
        for (int q = 0; q < 4; ++q) {
            int r = r0 + mi * 16 + (lane >> 4) * 4 + q;
            if (r < n) {
                #pragma unroll
                for (int nj = 0; nj < 4; ++nj) {
                    int cc = c0 + nj * 16 + (lane & 15);
                    gates[(size_t)r * 512 + cc] = f2bf(acc[mi][nj][q]);
                }
            }
        }
    }
}

// ---- Kernel 9: LSTM gate combine + write outputs ----
__global__ void k_combine(const unsigned short* __restrict__ gates,
                          const float* __restrict__ c,
                          const float* __restrict__ b, const float* __restrict__ wc,
                          float* __restrict__ out, int n) {
    int idx = blockIdx.x * blockDim.x + threadIdx.x;
    if (idx >= n * FD) return;
    int nr = idx >> 7, j = idx & (FD - 1);
    const unsigned short* grow = gates + (size_t)nr * (GATES * FD);
    float cv = c[idx];

    float gi = bf2f(grow[0 * FD + j]) + wc[0 * FD + j] * cv + b[0 * FD + j];
    float gf = bf2f(grow[1 * FD + j]) + wc[1 * FD + j] * cv + b[1 * FD + j];
    float gg = bf2f(grow[2 * FD + j]) + b[2 * FD + j];

    float iv = sigmoidf_(gi);
    float fv = sigmoidf_(gf);
    float cn = fv * cv + iv * tanhf(gg);

    float go = bf2f(grow[3 * FD + j]) + wc[2 * FD + j] * cn + b[3 * FD + j];
    float ov = sigmoidf_(go);
    float hn = ov * tanhf(cn);

    int NH = n * FD;
    out[idx]          = hn;
    out[NH + idx]     = hn;
    out[2 * NH + idx] = cn;
}

extern "C" void kernel_launch(void* const* d_in, const int* in_sizes, int n_in,
                              void* d_out, int out_size, void* d_ws, size_t ws_size,
                              hipStream_t stream) {
    const float* x   = (const float*)d_in[0];
    const float* ew  = (const float*)d_in[1];
    const float* h   = (const float*)d_in[2];
    const float* c   = (const float*)d_in[3];
    const float* Wx  = (const float*)d_in[4];
    const float* Wh  = (const float*)d_in[5];
    const float* b   = (const float*)d_in[6];
    const float* wc  = (const float*)d_in[7];
    const int*   src = (const int*)d_in[8];
    const int*   dst = (const int*)d_in[9];

    const int n = in_sizes[0] / FD;   // 20000
    const int E = in_sizes[1];        // 640000

    const int Mpad  = (n + 63) & ~63;         // 20032
    const int nfrag = (Mpad / 16) * 16;       // 20032 fragments (rb*16 + kb)

    // workspace layout (float-granular, 16B-aligned regions)
    float* deg  = (float*)d_ws;                      // n
    int*   cnt  = (int*)(deg + n);                   // n
    int*   off  = cnt + n;                           // n+4 (padded)
    int*   cur  = off + n + 4;                       // n
    int*   esrc = cur + n;                           // E
    float* ewgt = (float*)(esrc + E);                // E
    float* tx   = ewgt + E;                          // n*FD
    float* th   = tx + (size_t)n * FD;               // n*FD
    unsigned short* gates = (unsigned short*)(th + (size_t)n * FD);  // n*512 bf16
    unsigned short* Abf   = gates + (size_t)n * 512;                 // Mpad*512 bf16
    unsigned short* Wbf   = Abf + (size_t)Mpad * 512;                // 512*512 bf16

    hipMemsetAsync(deg, 0, (size_t)(2 * n) * sizeof(float), stream);

    k_hist<<<(E + 255) / 256, 256, 0, stream>>>(ew, src, dst, deg, cnt, E);
    k_node_dis<<<(n + 255) / 256, 256, 0, stream>>>(deg, n);
    k_scan<<<1, 1024, 0, stream>>>(cnt, off, n);
    hipMemcpyAsync(cur, off, (size_t)n * sizeof(int), hipMemcpyDeviceToDevice, stream);
    k_fill<<<(E + 255) / 256, 256, 0, stream>>>(ew, src, dst, deg, cur, esrc, ewgt, E);
    k_gather<<<(n + 1) / 2, 256, 0, stream>>>(x, h, off, esrc, ewgt, tx, th, n);

    k_pack_w<<<512 / 4, 256, 0, stream>>>(Wx, Wh, Wbf);
    k_pack_a<<<(nfrag + 3) / 4, 256, 0, stream>>>(x, tx, h, th, Abf, n, nfrag);

    const int nwaves = (Mpad / 64) * 8;              // 313*8 = 2504
    k_gemm_mfma<<<nwaves / 4, 256, 0, stream>>>(Abf, Wbf, gates, n);

    k_combine<<<(n * FD + 255) / 256, 256, 0, stream>>>(gates, c, b, wc, (float*)d_out, n);
}

// Round 4
// 211.189 us; speedup vs baseline: 3.4156x; 1.2680x over previous
//
#include <hip/hip_runtime.h>
#include <math.h>

#define FD 128
#define GATES 4

typedef __attribute__((ext_vector_type(8))) short bf16x8;
typedef __attribute__((ext_vector_type(4))) float f32x4;

__device__ __forceinline__ float sigmoidf_(float v) {
    return 1.0f / (1.0f + expf(-v));
}

__device__ __forceinline__ unsigned short f2bf(float f) {
    unsigned int u = __builtin_bit_cast(unsigned int, f);
    u += 0x7fffu + ((u >> 16) & 1u);           // RNE (finite values)
    return (unsigned short)(u >> 16);
}
__device__ __forceinline__ float bf2f(unsigned short s) {
    unsigned int u = ((unsigned int)s) << 16;
    return __builtin_bit_cast(float, u);
}
__device__ __forceinline__ float bflo(unsigned int u) {   // element 2j (low half)
    return __builtin_bit_cast(float, u << 16);
}
__device__ __forceinline__ float bfhi(unsigned int u) {   // element 2j+1 (high half)
    return __builtin_bit_cast(float, u & 0xffff0000u);
}
__device__ __forceinline__ unsigned int pack2bf(float lo, float hi) {
    return (unsigned int)f2bf(lo) | ((unsigned int)f2bf(hi) << 16);
}

// ---- Kernel 1: histogram: deg[src] += ew (float), cnt[dst] += 1 (int) ----
__global__ void k_hist(const float* __restrict__ ew, const int* __restrict__ src,
                       const int* __restrict__ dst, float* __restrict__ deg,
                       int* __restrict__ cnt, int E) {
    int e = blockIdx.x * blockDim.x + threadIdx.x;
    if (e < E) {
        atomicAdd(&deg[src[e]], ew[e]);
        atomicAdd(&cnt[dst[e]], 1);
    }
}

// ---- Kernel 2: dis = deg>0 ? rsqrt(max(deg,1e-12)) : 0  (in place) ----
__global__ void k_node_dis(float* __restrict__ deg, int n) {
    int i = blockIdx.x * blockDim.x + threadIdx.x;
    if (i < n) {
        float d = deg[i];
        deg[i] = (d > 0.0f) ? rsqrtf(fmaxf(d, 1e-12f)) : 0.0f;
    }
}

// ---- Kernel 3: h-nonzero flag (one ballot-reduced atomic per wave) ----
__global__ void k_flag(const float4* __restrict__ h4, int n4, int* __restrict__ flag) {
    int i = blockIdx.x * blockDim.x + threadIdx.x;
    bool nz = false;
    if (i < n4) {
        float4 v = h4[i];
        nz = (v.x != 0.f) | (v.y != 0.f) | (v.z != 0.f) | (v.w != 0.f);
    }
    unsigned long long m = __ballot(nz);
    if ((threadIdx.x & 63) == 0 && m) atomicOr(flag, 1);
}

// ---- Kernel 4: convert x (always) and h (if flag) to bf16 rows ----
__global__ void k_cvt(const float* __restrict__ x, const float* __restrict__ h,
                      unsigned short* __restrict__ xbf, unsigned short* __restrict__ hbf,
                      const int* __restrict__ hflag, int n8) {
    int i = blockIdx.x * blockDim.x + threadIdx.x;
    if (i >= n8) return;
    const float4* xp = reinterpret_cast<const float4*>(x) + (size_t)i * 2;
    float4 a = xp[0], bq = xp[1];
    uint4 o;
    o.x = pack2bf(a.x, a.y);  o.y = pack2bf(a.z, a.w);
    o.z = pack2bf(bq.x, bq.y); o.w = pack2bf(bq.z, bq.w);
    reinterpret_cast<uint4*>(xbf)[i] = o;
    if (*hflag) {
        const float4* hp = reinterpret_cast<const float4*>(h) + (size_t)i * 2;
        float4 cq = hp[0], dq = hp[1];
        uint4 o2;
        o2.x = pack2bf(cq.x, cq.y); o2.y = pack2bf(cq.z, cq.w);
        o2.z = pack2bf(dq.x, dq.y); o2.w = pack2bf(dq.z, dq.w);
        reinterpret_cast<uint4*>(hbf)[i] = o2;
    }
}

// ---- Kernel 5: exclusive scan of cnt -> off (single block) ----
__global__ __launch_bounds__(1024) void k_scan(const int* __restrict__ cnt,
                                               int* __restrict__ off, int n) {
    __shared__ int warp_sums[16];
    __shared__ int base_sh;
    if (threadIdx.x == 0) base_sh = 0;
    __syncthreads();

    const int lane = threadIdx.x & 63;
    const int wid  = threadIdx.x >> 6;

    for (int start = 0; start < n; start += 1024) {
        int i = start + (int)threadIdx.x;
        int v = (i < n) ? cnt[i] : 0;
        int s = v;
        #pragma unroll
        for (int d = 1; d < 64; d <<= 1) {
            int t = __shfl_up(s, d);
            if (lane >= d) s += t;
        }
        if (lane == 63) warp_sums[wid] = s;
        __syncthreads();
        if (wid == 0 && lane < 16) {
            int ws = warp_sums[lane];
            #pragma unroll
            for (int d = 1; d < 16; d <<= 1) {
                int t = __shfl_up(ws, d);
                if (lane >= d) ws += t;
            }
            warp_sums[lane] = ws;
        }
        __syncthreads();
        int wbase = (wid > 0) ? warp_sums[wid - 1] : 0;
        int excl  = base_sh + wbase + (s - v);
        if (i < n) off[i] = excl;
        int chunk_total = warp_sums[15];
        __syncthreads();
        if (threadIdx.x == 0) base_sh += chunk_total;
        __syncthreads();
    }
    if (threadIdx.x == 0) off[n] = base_sh;
}

// ---- Kernel 6: bucket fill: CSR-ordered (src, w_sym) per dst ----
__global__ void k_fill(const float* __restrict__ ew, const int* __restrict__ src,
                       const int* __restrict__ dst, const float* __restrict__ dis,
                       int* __restrict__ cur, int* __restrict__ esrc,
                       float* __restrict__ ewgt, int E) {
    int e = blockIdx.x * blockDim.x + threadIdx.x;
    if (e >= E) return;
    int s = src[e], d = dst[e];
    float w = -dis[s] * ew[e] * dis[d];
    int p = atomicAdd(&cur[d], 1);
    esrc[p] = s;
    ewgt[p] = w;
}

// ---- Kernel 7: gather (bf16 rows): tx[d] = sum w*x[src], th if h nonzero ----
// One wave per node; lane covers features 2j,2j+1 (uint = 2 bf16, 256 B/row).
__global__ __launch_bounds__(256) void k_gather_bf(
    const unsigned int* __restrict__ xw, const unsigned int* __restrict__ hw,
    const int* __restrict__ off, const int* __restrict__ esrc,
    const float* __restrict__ ewgt, const int* __restrict__ hflag,
    unsigned int* __restrict__ txw, unsigned int* __restrict__ thw, int n) {

    int d    = blockIdx.x * 4 + (threadIdx.x >> 6);
    int lane = threadIdx.x & 63;
    if (d >= n) return;
    const bool hasH = (*hflag) != 0;

    int p0 = off[d], p1 = off[d + 1];
    float ax0 = 0.f, ax1 = 0.f, ah0 = 0.f, ah1 = 0.f;
    int p = p0;

    if (hasH) {
        for (; p + 1 < p1; p += 2) {
            int   s0 = esrc[p],  s1 = esrc[p + 1];
            float w0 = ewgt[p],  w1 = ewgt[p + 1];
            unsigned int u0 = xw[(size_t)s0 * 64 + lane];
            unsigned int u1 = xw[(size_t)s1 * 64 + lane];
            unsigned int v0 = hw[(size_t)s0 * 64 + lane];
            unsigned int v1 = hw[(size_t)s1 * 64 + lane];
            ax0 = fmaf(w0, bflo(u0), ax0); ax1 = fmaf(w0, bfhi(u0), ax1);
            ah0 = fmaf(w0, bflo(v0), ah0); ah1 = fmaf(w0, bfhi(v0), ah1);
            ax0 = fmaf(w1, bflo(u1), ax0); ax1 = fmaf(w1, bfhi(u1), ax1);
            ah0 = fmaf(w1, bflo(v1), ah0); ah1 = fmaf(w1, bfhi(v1), ah1);
        }
        if (p < p1) {
            int s = esrc[p]; float w = ewgt[p];
            unsigned int u = xw[(size_t)s * 64 + lane];
            unsigned int v = hw[(size_t)s * 64 + lane];
            ax0 = fmaf(w, bflo(u), ax0); ax1 = fmaf(w, bfhi(u), ax1);
            ah0 = fmaf(w, bflo(v), ah0); ah1 = fmaf(w, bfhi(v), ah1);
        }
        txw[(size_t)d * 64 + lane] = pack2bf(ax0, ax1);
        thw[(size_t)d * 64 + lane] = pack2bf(ah0, ah1);
    } else {
        for (; p + 1 < p1; p += 2) {
            int   s0 = esrc[p],  s1 = esrc[p + 1];
            float w0 = ewgt[p],  w1 = ewgt[p + 1];
            unsigned int u0 = xw[(size_t)s0 * 64 + lane];
            unsigned int u1 = xw[(size_t)s1 * 64 + lane];
            ax0 = fmaf(w0, bflo(u0), ax0); ax1 = fmaf(w0, bfhi(u0), ax1);
            ax0 = fmaf(w1, bflo(u1), ax0); ax1 = fmaf(w1, bfhi(u1), ax1);
        }
        if (p < p1) {
            int s = esrc[p]; float w = ewgt[p];
            unsigned int u = xw[(size_t)s * 64 + lane];
            ax0 = fmaf(w, bflo(u), ax0); ax1 = fmaf(w, bfhi(u), ax1);
        }
        txw[(size_t)d * 64 + lane] = pack2bf(ax0, ax1);
        // th never read when hflag==0 (pack_a/GEMM skip it) — no store needed
    }
}

// ---- Kernel 8: pack A = [x|tx|h|th] (bf16 rows) into fragment order ----
// Pure permutation copy: uint4 = 8 bf16 per lane.
__global__ __launch_bounds__(256) void k_pack_a(
    const unsigned short* __restrict__ xbf,  const unsigned short* __restrict__ txbf,
    const unsigned short* __restrict__ hbf,  const unsigned short* __restrict__ thbf,
    const int* __restrict__ hflag,
    unsigned short* __restrict__ Abf, int n, int nfrag) {

    int frag = blockIdx.x * 4 + (threadIdx.x >> 6);
    if (frag >= nfrag) return;
    int lane = threadIdx.x & 63;
    int rb = frag >> 4, kb = frag & 15;
    if (kb >= 8 && *hflag == 0) return;     // h-half never read by GEMM then

    int r  = rb * 16 + (lane & 15);
    int k0 = kb * 32 + (lane >> 4) * 8;
    const unsigned short* srcp = (kb < 4) ? xbf : (kb < 8) ? txbf : (kb < 12) ? hbf : thbf;
    int col = k0 & (FD - 1);

    uint4 v = make_uint4(0u, 0u, 0u, 0u);
    if (r < n) v = *reinterpret_cast<const uint4*>(srcp + (size_t)r * FD + col);
    *reinterpret_cast<uint4*>(Abf + (size_t)frag * 512 + lane * 8) = v;
}

// ---- Kernel 9: pack Wcat (512x512) into B-fragment-ordered bf16 ----
__global__ void k_pack_w(const float* __restrict__ Wx, const float* __restrict__ Wh,
                         unsigned short* __restrict__ Wbf) {
    int frag = blockIdx.x * 4 + (threadIdx.x >> 6);   // 0..511
    int lane = threadIdx.x & 63;
    int cb = frag >> 4, kb = frag & 15;
    int col = cb * 16 + (lane & 15);
    int k0  = kb * 32 + (lane >> 4) * 8;

    int sel  = k0 >> 7;                // 0..3 : Wx0, Wx1, Wh0, Wh1
    int g    = col >> 7;
    int j    = col & (FD - 1);
    const float* Wb = (sel < 2) ? Wx : Wh;
    const float* p = Wb + (((size_t)g * 2 + (sel & 1)) * FD + (k0 & (FD - 1))) * FD + j;

    unsigned short outv[8];
    #pragma unroll
    for (int i = 0; i < 8; ++i) outv[i] = f2bf(p[(size_t)i * FD]);

    *reinterpret_cast<uint4*>(Wbf + (size_t)frag * 512 + lane * 8) =
        *reinterpret_cast<uint4*>(outv);
}

// ---- Kernel 10: MFMA GEMM: gates(bf16, N x 512) = Abf @ Wbf ----
// K halves (kb<8) when h==0. No LDS; fragment-ordered coalesced loads.
__global__ __launch_bounds__(256) void k_gemm_mfma(
    const unsigned short* __restrict__ Abf, const unsigned short* __restrict__ Wbf,
    const int* __restrict__ hflag,
    unsigned short* __restrict__ gates, int n) {

    int wg   = blockIdx.x * 4 + (threadIdx.x >> 6);
    int lane = threadIdx.x & 63;
    int rt = wg >> 3;
    int ct = wg & 7;
    const int kbmax = (*hflag) ? 16 : 8;

    f32x4 acc[4][4];
    #pragma unroll
    for (int mi = 0; mi < 4; ++mi)
        #pragma unroll
        for (int nj = 0; nj < 4; ++nj)
            acc[mi][nj] = (f32x4)0.0f;

    const size_t aoff = ((size_t)(rt * 4) * 16) * 512 + lane * 8;
    const size_t boff = ((size_t)(ct * 4) * 16) * 512 + lane * 8;

    for (int kb = 0; kb < kbmax; ++kb) {
        bf16x8 a[4], b[4];
        #pragma unroll
        for (int mi = 0; mi < 4; ++mi)
            a[mi] = *reinterpret_cast<const bf16x8*>(Abf + aoff + (size_t)(mi * 16 + kb) * 512);
        #pragma unroll
        for (int nj = 0; nj < 4; ++nj)
            b[nj] = *reinterpret_cast<const bf16x8*>(Wbf + boff + (size_t)(nj * 16 + kb) * 512);
        #pragma unroll
        for (int mi = 0; mi < 4; ++mi)
            #pragma unroll
            for (int nj = 0; nj < 4; ++nj)
                acc[mi][nj] = __builtin_amdgcn_mfma_f32_16x16x32_bf16(
                                  a[mi], b[nj], acc[mi][nj], 0, 0, 0);
    }

    const int r0 = rt * 64, c0 = ct * 64;
    #pragma unroll
    for (int mi = 0; mi < 4; ++mi) {
        #pragma unroll
        for (int q = 0; q < 4; ++q) {
            int r = r0 + mi * 16 + (lane >> 4) * 4 + q;
            if (r < n) {
                #pragma unroll
                for (int nj = 0; nj < 4; ++nj) {
                    int cc = c0 + nj * 16 + (lane & 15);
                    gates[(size_t)r * 512 + cc] = f2bf(acc[mi][nj][q]);
                }
            }
        }
    }
}

// ---- Kernel 11: LSTM gate combine + write outputs ----
__global__ void k_combine(const unsigned short* __restrict__ gates,
                          const float* __restrict__ c,
                          const float* __restrict__ b, const float* __restrict__ wc,
                          float* __restrict__ out, int n) {
    int idx = blockIdx.x * blockDim.x + threadIdx.x;
    if (idx >= n * FD) return;
    int nr = idx >> 7, j = idx & (FD - 1);
    const unsigned short* grow = gates + (size_t)nr * (GATES * FD);
    float cv = c[idx];

    float gi = bf2f(grow[0 * FD + j]) + wc[0 * FD + j] * cv + b[0 * FD + j];
    float gf = bf2f(grow[1 * FD + j]) + wc[1 * FD + j] * cv + b[1 * FD + j];
    float gg = bf2f(grow[2 * FD + j]) + b[2 * FD + j];

    float iv = sigmoidf_(gi);
    float fv = sigmoidf_(gf);
    float cn = fv * cv + iv * tanhf(gg);

    float go = bf2f(grow[3 * FD + j]) + wc[2 * FD + j] * cn + b[3 * FD + j];
    float ov = sigmoidf_(go);
    float hn = ov * tanhf(cn);

    int NH = n * FD;
    out[idx]          = hn;
    out[NH + idx]     = hn;
    out[2 * NH + idx] = cn;
}

extern "C" void kernel_launch(void* const* d_in, const int* in_sizes, int n_in,
                              void* d_out, int out_size, void* d_ws, size_t ws_size,
                              hipStream_t stream) {
    const float* x   = (const float*)d_in[0];
    const float* ew  = (const float*)d_in[1];
    const float* h   = (const float*)d_in[2];
    const float* c   = (const float*)d_in[3];
    const float* Wx  = (const float*)d_in[4];
    const float* Wh  = (const float*)d_in[5];
    const float* b   = (const float*)d_in[6];
    const float* wc  = (const float*)d_in[7];
    const int*   src = (const int*)d_in[8];
    const int*   dst = (const int*)d_in[9];

    const int n = in_sizes[0] / FD;   // 20000
    const int E = in_sizes[1];        // 640000

    const int Mpad  = (n + 63) & ~63;         // 20032
    const int nfrag = (Mpad / 16) * 16;       // fragment count (rb*16 + kb)

    // ---- workspace layout (16B-aligned regions) ----
    float* deg   = (float*)d_ws;                          // n
    int*   cnt   = (int*)(deg + n);                       // n
    int*   hflag = cnt + n;                               // 4 (flag + pad)
    int*   off   = hflag + 4;                             // n+4
    int*   cur   = off + n + 4;                           // n
    int*   esrc  = cur + n;                               // E
    float* ewgt  = (float*)(esrc + E);                    // E
    unsigned short* txbf = (unsigned short*)(ewgt + E);   // n*FD bf16
    unsigned short* thbf = txbf + (size_t)n * FD;         // n*FD
    unsigned short* xbf  = thbf + (size_t)n * FD;         // n*FD
    unsigned short* hbf  = xbf + (size_t)n * FD;          // n*FD
    unsigned short* gates= hbf + (size_t)n * FD;          // n*512
    unsigned short* Abf  = gates + (size_t)n * 512;       // Mpad*512
    unsigned short* Wbf  = Abf + (size_t)Mpad * 512;      // 512*512

    // zero deg (n) + cnt (n) + hflag (4)
    hipMemsetAsync(deg, 0, (size_t)(2 * n + 4) * sizeof(float), stream);

    k_flag<<<(n * FD / 4 + 255) / 256, 256, 0, stream>>>((const float4*)h, n * FD / 4, hflag);
    k_cvt<<<(n * FD / 8 + 255) / 256, 256, 0, stream>>>(x, h, xbf, hbf, hflag, n * FD / 8);

    k_hist<<<(E + 255) / 256, 256, 0, stream>>>(ew, src, dst, deg, cnt, E);
    k_node_dis<<<(n + 255) / 256, 256, 0, stream>>>(deg, n);
    k_scan<<<1, 1024, 0, stream>>>(cnt, off, n);
    hipMemcpyAsync(cur, off, (size_t)n * sizeof(int), hipMemcpyDeviceToDevice, stream);
    k_fill<<<(E + 255) / 256, 256, 0, stream>>>(ew, src, dst, deg, cur, esrc, ewgt, E);

    k_gather_bf<<<(n + 3) / 4, 256, 0, stream>>>(
        (const unsigned int*)xbf, (const unsigned int*)hbf, off, esrc, ewgt, hflag,
        (unsigned int*)txbf, (unsigned int*)thbf, n);

    k_pack_w<<<512 / 4, 256, 0, stream>>>(Wx, Wh, Wbf);
    k_pack_a<<<(nfrag + 3) / 4, 256, 0, stream>>>(xbf, txbf, hbf, thbf, hflag, Abf, n, nfrag);

    const int nwaves = (Mpad / 64) * 8;
    k_gemm_mfma<<<nwaves / 4, 256, 0, stream>>>(Abf, Wbf, hflag, gates, n);

    k_combine<<<(n * FD + 255) / 256, 256, 0, stream>>>(gates, c, b, wc, (float*)d_out, n);
}

// Round 5
// 206.630 us; speedup vs baseline: 3.4910x; 1.0221x over previous
//
#include <hip/hip_runtime.h>
#include <math.h>

#define FD 128
#define GATES 4
#define NC 32            // histogram privatization copies

typedef __attribute__((ext_vector_type(8))) short bf16x8;
typedef __attribute__((ext_vector_type(4))) float f32x4;

__device__ __forceinline__ float sigmoidf_(float v) {
    return 1.0f / (1.0f + expf(-v));
}

__device__ __forceinline__ unsigned short f2bf(float f) {
    unsigned int u = __builtin_bit_cast(unsigned int, f);
    u += 0x7fffu + ((u >> 16) & 1u);           // RNE (finite values)
    return (unsigned short)(u >> 16);
}
__device__ __forceinline__ float bf2f(unsigned short s) {
    unsigned int u = ((unsigned int)s) << 16;
    return __builtin_bit_cast(float, u);
}
__device__ __forceinline__ float bflo(unsigned int u) {
    return __builtin_bit_cast(float, u << 16);
}
__device__ __forceinline__ float bfhi(unsigned int u) {
    return __builtin_bit_cast(float, u & 0xffff0000u);
}
__device__ __forceinline__ unsigned int pack2bf(float lo, float hi) {
    return (unsigned int)f2bf(lo) | ((unsigned int)f2bf(hi) << 16);
}

// ---- Kernel 1: multi-copy histogram: deg_c[c][src] += ew, cnt_c[c][dst]++ ----
__global__ void k_hist_mc(const float* __restrict__ ew, const int* __restrict__ src,
                          const int* __restrict__ dst, float* __restrict__ deg_c,
                          int* __restrict__ cnt_c, int E, int S) {
    int e = blockIdx.x * blockDim.x + threadIdx.x;
    if (e >= E) return;
    int c = blockIdx.x & (NC - 1);
    atomicAdd(&deg_c[(size_t)c * S + src[e]], ew[e]);
    atomicAdd(&cnt_c[(size_t)c * S + dst[e]], 1);
}

// ---- Kernel 2: fold copies: dis = rsqrt(deg), cnt = sum ----
__global__ void k_prep(const float* __restrict__ deg_c, const int* __restrict__ cnt_c,
                       float* __restrict__ dis, int* __restrict__ cnt, int n, int S) {
    int d = blockIdx.x * blockDim.x + threadIdx.x;
    if (d >= n) return;
    float s = 0.f; int ct = 0;
    #pragma unroll 4
    for (int c = 0; c < NC; ++c) {
        s  += deg_c[(size_t)c * S + d];
        ct += cnt_c[(size_t)c * S + d];
    }
    dis[d] = (s > 0.0f) ? rsqrtf(fmaxf(s, 1e-12f)) : 0.0f;
    cnt[d] = ct;
}

// ---- Kernel 3: h-nonzero flag ----
__global__ void k_flag(const float4* __restrict__ h4, int n4, int* __restrict__ flag) {
    int i = blockIdx.x * blockDim.x + threadIdx.x;
    bool nz = false;
    if (i < n4) {
        float4 v = h4[i];
        nz = (v.x != 0.f) | (v.y != 0.f) | (v.z != 0.f) | (v.w != 0.f);
    }
    unsigned long long m = __ballot(nz);
    if ((threadIdx.x & 63) == 0 && m) atomicOr(flag, 1);
}

// ---- Kernel 4: convert x (always) and h (if flag) to bf16 rows ----
__global__ void k_cvt(const float* __restrict__ x, const float* __restrict__ h,
                      unsigned short* __restrict__ xbf, unsigned short* __restrict__ hbf,
                      const int* __restrict__ hflag, int n8) {
    int i = blockIdx.x * blockDim.x + threadIdx.x;
    if (i >= n8) return;
    const float4* xp = reinterpret_cast<const float4*>(x) + (size_t)i * 2;
    float4 a = xp[0], bq = xp[1];
    uint4 o;
    o.x = pack2bf(a.x, a.y);  o.y = pack2bf(a.z, a.w);
    o.z = pack2bf(bq.x, bq.y); o.w = pack2bf(bq.z, bq.w);
    reinterpret_cast<uint4*>(xbf)[i] = o;
    if (*hflag) {
        const float4* hp = reinterpret_cast<const float4*>(h) + (size_t)i * 2;
        float4 cq = hp[0], dq = hp[1];
        uint4 o2;
        o2.x = pack2bf(cq.x, cq.y); o2.y = pack2bf(cq.z, cq.w);
        o2.z = pack2bf(dq.x, dq.y); o2.w = pack2bf(dq.z, dq.w);
        reinterpret_cast<uint4*>(hbf)[i] = o2;
    }
}

// ---- Kernel 5: exclusive scan of cnt -> off (single block) ----
__global__ __launch_bounds__(1024) void k_scan(const int* __restrict__ cnt,
                                               int* __restrict__ off, int n) {
    __shared__ int warp_sums[16];
    __shared__ int base_sh;
    if (threadIdx.x == 0) base_sh = 0;
    __syncthreads();

    const int lane = threadIdx.x & 63;
    const int wid  = threadIdx.x >> 6;

    for (int start = 0; start < n; start += 1024) {
        int i = start + (int)threadIdx.x;
        int v = (i < n) ? cnt[i] : 0;
        int s = v;
        #pragma unroll
        for (int d = 1; d < 64; d <<= 1) {
            int t = __shfl_up(s, d);
            if (lane >= d) s += t;
        }
        if (lane == 63) warp_sums[wid] = s;
        __syncthreads();
        if (wid == 0 && lane < 16) {
            int ws = warp_sums[lane];
            #pragma unroll
            for (int d = 1; d < 16; d <<= 1) {
                int t = __shfl_up(ws, d);
                if (lane >= d) ws += t;
            }
            warp_sums[lane] = ws;
        }
        __syncthreads();
        int wbase = (wid > 0) ? warp_sums[wid - 1] : 0;
        int excl  = base_sh + wbase + (s - v);
        if (i < n) off[i] = excl;
        int chunk_total = warp_sums[15];
        __syncthreads();
        if (threadIdx.x == 0) base_sh += chunk_total;
        __syncthreads();
    }
    if (threadIdx.x == 0) off[n] = base_sh;
}

// ---- Kernel 6: per-copy CSR cursors: cur_c[c][d] = off[d] + prefix_c(cnt_c) ----
__global__ void k_setcur(const int* __restrict__ cnt_c, const int* __restrict__ off,
                         int* __restrict__ cur_c, int n, int S) {
    int d = blockIdx.x * blockDim.x + threadIdx.x;
    if (d >= n) return;
    int run = off[d];
    #pragma unroll 4
    for (int c = 0; c < NC; ++c) {
        cur_c[(size_t)c * S + d] = run;
        run += cnt_c[(size_t)c * S + d];
    }
}

// ---- Kernel 7: bucket fill with per-copy cursors ----
__global__ void k_fill_mc(const float* __restrict__ ew, const int* __restrict__ src,
                          const int* __restrict__ dst, const float* __restrict__ dis,
                          int* __restrict__ cur_c, int* __restrict__ esrc,
                          float* __restrict__ ewgt, int E, int S) {
    int e = blockIdx.x * blockDim.x + threadIdx.x;
    if (e >= E) return;
    int c = blockIdx.x & (NC - 1);
    int s = src[e], d = dst[e];
    float w = -dis[s] * ew[e] * dis[d];
    int p = atomicAdd(&cur_c[(size_t)c * S + d], 1);
    esrc[p] = s;
    ewgt[p] = w;
}

// ---- Kernel 8: gather (bf16 rows) ----
__global__ __launch_bounds__(256) void k_gather_bf(
    const unsigned int* __restrict__ xw, const unsigned int* __restrict__ hw,
    const int* __restrict__ off, const int* __restrict__ esrc,
    const float* __restrict__ ewgt, const int* __restrict__ hflag,
    unsigned int* __restrict__ txw, unsigned int* __restrict__ thw, int n) {

    int d    = blockIdx.x * 4 + (threadIdx.x >> 6);
    int lane = threadIdx.x & 63;
    if (d >= n) return;
    const bool hasH = (*hflag) != 0;

    int p0 = off[d], p1 = off[d + 1];
    float ax0 = 0.f, ax1 = 0.f, ah0 = 0.f, ah1 = 0.f;
    int p = p0;

    if (hasH) {
        for (; p + 1 < p1; p += 2) {
            int   s0 = esrc[p],  s1 = esrc[p + 1];
            float w0 = ewgt[p],  w1 = ewgt[p + 1];
            unsigned int u0 = xw[(size_t)s0 * 64 + lane];
            unsigned int u1 = xw[(size_t)s1 * 64 + lane];
            unsigned int v0 = hw[(size_t)s0 * 64 + lane];
            unsigned int v1 = hw[(size_t)s1 * 64 + lane];
            ax0 = fmaf(w0, bflo(u0), ax0); ax1 = fmaf(w0, bfhi(u0), ax1);
            ah0 = fmaf(w0, bflo(v0), ah0); ah1 = fmaf(w0, bfhi(v0), ah1);
            ax0 = fmaf(w1, bflo(u1), ax0); ax1 = fmaf(w1, bfhi(u1), ax1);
            ah0 = fmaf(w1, bflo(v1), ah0); ah1 = fmaf(w1, bfhi(v1), ah1);
        }
        if (p < p1) {
            int s = esrc[p]; float w = ewgt[p];
            unsigned int u = xw[(size_t)s * 64 + lane];
            unsigned int v = hw[(size_t)s * 64 + lane];
            ax0 = fmaf(w, bflo(u), ax0); ax1 = fmaf(w, bfhi(u), ax1);
            ah0 = fmaf(w, bflo(v), ah0); ah1 = fmaf(w, bfhi(v), ah1);
        }
        txw[(size_t)d * 64 + lane] = pack2bf(ax0, ax1);
        thw[(size_t)d * 64 + lane] = pack2bf(ah0, ah1);
    } else {
        for (; p + 1 < p1; p += 2) {
            int   s0 = esrc[p],  s1 = esrc[p + 1];
            float w0 = ewgt[p],  w1 = ewgt[p + 1];
            unsigned int u0 = xw[(size_t)s0 * 64 + lane];
            unsigned int u1 = xw[(size_t)s1 * 64 + lane];
            ax0 = fmaf(w0, bflo(u0), ax0); ax1 = fmaf(w0, bfhi(u0), ax1);
            ax0 = fmaf(w1, bflo(u1), ax0); ax1 = fmaf(w1, bfhi(u1), ax1);
        }
        if (p < p1) {
            int s = esrc[p]; float w = ewgt[p];
            unsigned int u = xw[(size_t)s * 64 + lane];
            ax0 = fmaf(w, bflo(u), ax0); ax1 = fmaf(w, bfhi(u), ax1);
        }
        txw[(size_t)d * 64 + lane] = pack2bf(ax0, ax1);
    }
}

// ---- Kernel 9: pack A = [x|tx|h|th] (bf16 rows) into fragment order ----
__global__ __launch_bounds__(256) void k_pack_a(
    const unsigned short* __restrict__ xbf,  const unsigned short* __restrict__ txbf,
    const unsigned short* __restrict__ hbf,  const unsigned short* __restrict__ thbf,
    const int* __restrict__ hflag,
    unsigned short* __restrict__ Abf, int n, int nfrag) {

    int frag = blockIdx.x * 4 + (threadIdx.x >> 6);
    if (frag >= nfrag) return;
    int lane = threadIdx.x & 63;
    int rb = frag >> 4, kb = frag & 15;
    if (kb >= 8 && *hflag == 0) return;

    int r  = rb * 16 + (lane & 15);
    int k0 = kb * 32 + (lane >> 4) * 8;
    const unsigned short* srcp = (kb < 4) ? xbf : (kb < 8) ? txbf : (kb < 12) ? hbf : thbf;
    int col = k0 & (FD - 1);

    uint4 v = make_uint4(0u, 0u, 0u, 0u);
    if (r < n) v = *reinterpret_cast<const uint4*>(srcp + (size_t)r * FD + col);
    *reinterpret_cast<uint4*>(Abf + (size_t)frag * 512 + lane * 8) = v;
}

// ---- Kernel 10: pack Wcat into B-fragment order ----
__global__ void k_pack_w(const float* __restrict__ Wx, const float* __restrict__ Wh,
                         unsigned short* __restrict__ Wbf) {
    int frag = blockIdx.x * 4 + (threadIdx.x >> 6);   // 0..511
    int lane = threadIdx.x & 63;
    int cb = frag >> 4, kb = frag & 15;
    int col = cb * 16 + (lane & 15);
    int k0  = kb * 32 + (lane >> 4) * 8;

    int sel  = k0 >> 7;
    int g    = col >> 7;
    int j    = col & (FD - 1);
    const float* Wb = (sel < 2) ? Wx : Wh;
    const float* p = Wb + (((size_t)g * 2 + (sel & 1)) * FD + (k0 & (FD - 1))) * FD + j;

    unsigned short outv[8];
    #pragma unroll
    for (int i = 0; i < 8; ++i) outv[i] = f2bf(p[(size_t)i * FD]);

    *reinterpret_cast<uint4*>(Wbf + (size_t)frag * 512 + lane * 8) =
        *reinterpret_cast<uint4*>(outv);
}

// ---- Kernel 11: MFMA GEMM ----
__global__ __launch_bounds__(256) void k_gemm_mfma(
    const unsigned short* __restrict__ Abf, const unsigned short* __restrict__ Wbf,
    const int* __restrict__ hflag,
    unsigned short* __restrict__ gates, int n) {

    int wg   = blockIdx.x * 4 + (threadIdx.x >> 6);
    int lane = threadIdx.x & 63;
    int rt = wg >> 3;
    int ct = wg & 7;
    const int kbmax = (*hflag) ? 16 : 8;

    f32x4 acc[4][4];
    #pragma unroll
    for (int mi = 0; mi < 4; ++mi)
        #pragma unroll
        for (int nj = 0; nj < 4; ++nj)
            acc[mi][nj] = (f32x4)0.0f;

    const size_t aoff = ((size_t)(rt * 4) * 16) * 512 + lane * 8;
    const size_t boff = ((size_t)(ct * 4) * 16) * 512 + lane * 8;

    for (int kb = 0; kb < kbmax; ++kb) {
        bf16x8 a[4], b[4];
        #pragma unroll
        for (int mi = 0; mi < 4; ++mi)
            a[mi] = *reinterpret_cast<const bf16x8*>(Abf + aoff + (size_t)(mi * 16 + kb) * 512);
        #pragma unroll
        for (int nj = 0; nj < 4; ++nj)
            b[nj] = *reinterpret_cast<const bf16x8*>(Wbf + boff + (size_t)(nj * 16 + kb) * 512);
        #pragma unroll
        for (int mi = 0; mi < 4; ++mi)
            #pragma unroll
            for (int nj = 0; nj < 4; ++nj)
                acc[mi][nj] = __builtin_amdgcn_mfma_f32_16x16x32_bf16(
                                  a[mi], b[nj], acc[mi][nj], 0, 0, 0);
    }

    const int r0 = rt * 64, c0 = ct * 64;
    #pragma unroll
    for (int mi = 0; mi < 4; ++mi) {
        #pragma unroll
        for (int q = 0; q < 4; ++q) {
            int r = r0 + mi * 16 + (lane >> 4) * 4 + q;
            if (r < n) {
                #pragma unroll
                for (int nj = 0; nj < 4; ++nj) {
                    int cc = c0 + nj * 16 + (lane & 15);
                    gates[(size_t)r * 512 + cc] = f2bf(acc[mi][nj][q]);
                }
            }
        }
    }
}

// ---- Kernel 12: LSTM gate combine + write outputs ----
__global__ void k_combine(const unsigned short* __restrict__ gates,
                          const float* __restrict__ c,
                          const float* __restrict__ b, const float* __restrict__ wc,
                          float* __restrict__ out, int n) {
    int idx = blockIdx.x * blockDim.x + threadIdx.x;
    if (idx >= n * FD) return;
    int nr = idx >> 7, j = idx & (FD - 1);
    const unsigned short* grow = gates + (size_t)nr * (GATES * FD);
    float cv = c[idx];

    float gi = bf2f(grow[0 * FD + j]) + wc[0 * FD + j] * cv + b[0 * FD + j];
    float gf = bf2f(grow[1 * FD + j]) + wc[1 * FD + j] * cv + b[1 * FD + j];
    float gg = bf2f(grow[2 * FD + j]) + b[2 * FD + j];

    float iv = sigmoidf_(gi);
    float fv = sigmoidf_(gf);
    float cn = fv * cv + iv * tanhf(gg);

    float go = bf2f(grow[3 * FD + j]) + wc[2 * FD + j] * cn + b[3 * FD + j];
    float ov = sigmoidf_(go);
    float hn = ov * tanhf(cn);

    int NH = n * FD;
    out[idx]          = hn;
    out[NH + idx]     = hn;
    out[2 * NH + idx] = cn;
}

extern "C" void kernel_launch(void* const* d_in, const int* in_sizes, int n_in,
                              void* d_out, int out_size, void* d_ws, size_t ws_size,
                              hipStream_t stream) {
    const float* x   = (const float*)d_in[0];
    const float* ew  = (const float*)d_in[1];
    const float* h   = (const float*)d_in[2];
    const float* c   = (const float*)d_in[3];
    const float* Wx  = (const float*)d_in[4];
    const float* Wh  = (const float*)d_in[5];
    const float* b   = (const float*)d_in[6];
    const float* wc  = (const float*)d_in[7];
    const int*   src = (const int*)d_in[8];
    const int*   dst = (const int*)d_in[9];

    const int n = in_sizes[0] / FD;   // 20000
    const int E = in_sizes[1];        // 640000

    const int Mpad  = (n + 63) & ~63;         // 20032
    const int nfrag = (Mpad / 16) * 16;
    const int S     = Mpad + 64;              // copy stride (not a 4KB multiple)

    // ---- workspace layout ----
    float* dis   = (float*)d_ws;                          // n
    int*   cnt   = (int*)(dis + n);                       // n
    int*   off   = cnt + n;                               // n+4
    int*   hflag = off + n + 4;                           // 4
    float* deg_c = (float*)(hflag + 4);                   // NC*S
    int*   cnt_c = (int*)(deg_c + (size_t)NC * S);        // NC*S
    int*   esrc  = cnt_c + (size_t)NC * S;                // E
    float* ewgt  = (float*)(esrc + E);                    // E
    unsigned short* txbf = (unsigned short*)(ewgt + E);   // n*FD bf16
    unsigned short* thbf = txbf + (size_t)n * FD;         // n*FD
    unsigned short* xbf  = thbf + (size_t)n * FD;         // n*FD
    unsigned short* hbf  = xbf + (size_t)n * FD;          // n*FD
    unsigned short* gates= hbf + (size_t)n * FD;          // n*512
    unsigned short* Abf  = gates + (size_t)n * 512;       // Mpad*512
    unsigned short* Wbf  = Abf + (size_t)Mpad * 512;      // 512*512
    int*   cur_c = (int*)Abf;   // aliases Abf: consumed by k_fill_mc before pack_a writes

    // zero hflag + deg_c + cnt_c (contiguous)
    hipMemsetAsync(hflag, 0, (4 + 2 * (size_t)NC * S) * sizeof(int), stream);

    k_flag<<<(n * FD / 4 + 255) / 256, 256, 0, stream>>>((const float4*)h, n * FD / 4, hflag);
    k_cvt<<<(n * FD / 8 + 255) / 256, 256, 0, stream>>>(x, h, xbf, hbf, hflag, n * FD / 8);

    k_hist_mc<<<(E + 255) / 256, 256, 0, stream>>>(ew, src, dst, deg_c, cnt_c, E, S);
    k_prep<<<(n + 255) / 256, 256, 0, stream>>>(deg_c, cnt_c, dis, cnt, n, S);
    k_scan<<<1, 1024, 0, stream>>>(cnt, off, n);
    k_setcur<<<(n + 255) / 256, 256, 0, stream>>>(cnt_c, off, cur_c, n, S);
    k_fill_mc<<<(E + 255) / 256, 256, 0, stream>>>(ew, src, dst, dis, cur_c, esrc, ewgt, E, S);

    k_gather_bf<<<(n + 3) / 4, 256, 0, stream>>>(
        (const unsigned int*)xbf, (const unsigned int*)hbf, off, esrc, ewgt, hflag,
        (unsigned int*)txbf, (unsigned int*)thbf, n);

    k_pack_w<<<512 / 4, 256, 0, stream>>>(Wx, Wh, Wbf);
    k_pack_a<<<(nfrag + 3) / 4, 256, 0, stream>>>(xbf, txbf, hbf, thbf, hflag, Abf, n, nfrag);

    const int nwaves = (Mpad / 64) * 8;
    k_gemm_mfma<<<nwaves / 4, 256, 0, stream>>>(Abf, Wbf, hflag, gates, n);

    k_combine<<<(n * FD + 255) / 256, 256, 0, stream>>>(gates, c, b, wc, (float*)d_out, n);
}

// Round 6
// 174.598 us; speedup vs baseline: 4.1314x; 1.1835x over previous
//
#include <hip/hip_runtime.h>
#include <math.h>

#define FD 128
#define GATES 4
#define NB  128            // edge chunks (per-chunk private histograms)
#define NRH 4              // node ranges for hist (LDS = (n/NRH)*(4+4) B <= 41 KB)
#define NRF 2              // node ranges for fill (LDS = (n/NRF)*4 B <= 41 KB)
#define RSH_MAX 5088       // max nodes per hist range
#define RSF_MAX 10176      // max nodes per fill range

typedef __attribute__((ext_vector_type(8))) short bf16x8;
typedef __attribute__((ext_vector_type(4))) float f32x4;

__device__ __forceinline__ float sigmoidf_(float v) {
    return 1.0f / (1.0f + expf(-v));
}

__device__ __forceinline__ unsigned short f2bf(float f) {
    unsigned int u = __builtin_bit_cast(unsigned int, f);
    u += 0x7fffu + ((u >> 16) & 1u);           // RNE (finite values)
    return (unsigned short)(u >> 16);
}
__device__ __forceinline__ float bf2f(unsigned short s) {
    unsigned int u = ((unsigned int)s) << 16;
    return __builtin_bit_cast(float, u);
}
__device__ __forceinline__ float bflo(unsigned int u) {
    return __builtin_bit_cast(float, u << 16);
}
__device__ __forceinline__ float bfhi(unsigned int u) {
    return __builtin_bit_cast(float, u & 0xffff0000u);
}
__device__ __forceinline__ unsigned int pack2bf(float lo, float hi) {
    return (unsigned int)f2bf(lo) | ((unsigned int)f2bf(hi) << 16);
}

// ---- Kernel 1: LDS-private histogram over (chunk b, node-range r) ----
// deg_priv[b][d] = sum of ew over chunk-b edges with src==d
// cnt_priv[b][d] = count of chunk-b edges with dst==d
// No device atomics: LDS atomics + coalesced private writeback.
__global__ __launch_bounds__(256) void k_hist_lds(
    const float* __restrict__ ew, const int* __restrict__ src,
    const int* __restrict__ dst,
    float* __restrict__ deg_priv, unsigned short* __restrict__ cnt_priv,
    int E, int n, int ech, int rs) {

    __shared__ float        degL[RSH_MAX];
    __shared__ unsigned int cntL[RSH_MAX];

    const int b = blockIdx.x & (NB - 1);
    const int r = blockIdx.x >> 7;            // NB==128
    const int base = r * rs;
    const int rse  = min(rs, n - base);

    for (int i = threadIdx.x; i < rse; i += 256) { degL[i] = 0.f; cntL[i] = 0u; }
    __syncthreads();

    const int e0 = b * ech, e1 = min(e0 + ech, E);
    for (int e = e0 + (int)threadIdx.x; e < e1; e += 256) {
        int s = src[e], d = dst[e];
        unsigned int rs_ = (unsigned int)(s - base);
        unsigned int rd_ = (unsigned int)(d - base);
        if (rs_ < (unsigned int)rse) atomicAdd(&degL[rs_], ew[e]);
        if (rd_ < (unsigned int)rse) atomicAdd(&cntL[rd_], 1u);
    }
    __syncthreads();

    float*          dp = deg_priv + (size_t)b * n + base;
    unsigned short* cp = cnt_priv + (size_t)b * n + base;
    for (int i = threadIdx.x; i < rse; i += 256) {
        dp[i] = degL[i];
        cp[i] = (unsigned short)cntL[i];
    }
}

// ---- Kernel 2: fold copies: dis = rsqrt(sum deg), cnt = sum cnt ----
__global__ void k_prep(const float* __restrict__ deg_priv,
                       const unsigned short* __restrict__ cnt_priv,
                       float* __restrict__ dis, int* __restrict__ cnt, int n) {
    int d = blockIdx.x * blockDim.x + threadIdx.x;
    if (d >= n) return;
    float s = 0.f; int ct = 0;
    #pragma unroll 4
    for (int b = 0; b < NB; ++b) {
        s  += deg_priv[(size_t)b * n + d];
        ct += (int)cnt_priv[(size_t)b * n + d];
    }
    dis[d] = (s > 0.0f) ? rsqrtf(fmaxf(s, 1e-12f)) : 0.0f;
    cnt[d] = ct;
}

// ---- Kernel 3: h-nonzero flag ----
__global__ void k_flag(const float4* __restrict__ h4, int n4, int* __restrict__ flag) {
    int i = blockIdx.x * blockDim.x + threadIdx.x;
    bool nz = false;
    if (i < n4) {
        float4 v = h4[i];
        nz = (v.x != 0.f) | (v.y != 0.f) | (v.z != 0.f) | (v.w != 0.f);
    }
    unsigned long long m = __ballot(nz);
    if ((threadIdx.x & 63) == 0 && m) atomicOr(flag, 1);
}

// ---- Kernel 4: convert x (always) and h (if flag) to bf16 rows ----
__global__ void k_cvt(const float* __restrict__ x, const float* __restrict__ h,
                      unsigned short* __restrict__ xbf, unsigned short* __restrict__ hbf,
                      const int* __restrict__ hflag, int n8) {
    int i = blockIdx.x * blockDim.x + threadIdx.x;
    if (i >= n8) return;
    const float4* xp = reinterpret_cast<const float4*>(x) + (size_t)i * 2;
    float4 a = xp[0], bq = xp[1];
    uint4 o;
    o.x = pack2bf(a.x, a.y);  o.y = pack2bf(a.z, a.w);
    o.z = pack2bf(bq.x, bq.y); o.w = pack2bf(bq.z, bq.w);
    reinterpret_cast<uint4*>(xbf)[i] = o;
    if (*hflag) {
        const float4* hp = reinterpret_cast<const float4*>(h) + (size_t)i * 2;
        float4 cq = hp[0], dq = hp[1];
        uint4 o2;
        o2.x = pack2bf(cq.x, cq.y); o2.y = pack2bf(cq.z, cq.w);
        o2.z = pack2bf(dq.x, dq.y); o2.w = pack2bf(dq.z, dq.w);
        reinterpret_cast<uint4*>(hbf)[i] = o2;
    }
}

// ---- Kernel 5: exclusive scan of cnt -> off (single block) ----
__global__ __launch_bounds__(1024) void k_scan(const int* __restrict__ cnt,
                                               int* __restrict__ off, int n) {
    __shared__ int warp_sums[16];
    __shared__ int base_sh;
    if (threadIdx.x == 0) base_sh = 0;
    __syncthreads();

    const int lane = threadIdx.x & 63;
    const int wid  = threadIdx.x >> 6;

    for (int start = 0; start < n; start += 1024) {
        int i = start + (int)threadIdx.x;
        int v = (i < n) ? cnt[i] : 0;
        int s = v;
        #pragma unroll
        for (int d = 1; d < 64; d <<= 1) {
            int t = __shfl_up(s, d);
            if (lane >= d) s += t;
        }
        if (lane == 63) warp_sums[wid] = s;
        __syncthreads();
        if (wid == 0 && lane < 16) {
            int ws = warp_sums[lane];
            #pragma unroll
            for (int d = 1; d < 16; d <<= 1) {
                int t = __shfl_up(ws, d);
                if (lane >= d) ws += t;
            }
            warp_sums[lane] = ws;
        }
        __syncthreads();
        int wbase = (wid > 0) ? warp_sums[wid - 1] : 0;
        int excl  = base_sh + wbase + (s - v);
        if (i < n) off[i] = excl;
        int chunk_total = warp_sums[15];
        __syncthreads();
        if (threadIdx.x == 0) base_sh += chunk_total;
        __syncthreads();
    }
    if (threadIdx.x == 0) off[n] = base_sh;
}

// ---- Kernel 6: column scan: curb[b][d] = off[d] + prefix_b(cnt_priv) ----
__global__ void k_colscan(const unsigned short* __restrict__ cnt_priv,
                          const int* __restrict__ off,
                          int* __restrict__ curb, int n) {
    int d = blockIdx.x * blockDim.x + threadIdx.x;
    if (d >= n) return;
    int run = off[d];
    #pragma unroll 4
    for (int b = 0; b < NB; ++b) {
        curb[(size_t)b * n + d] = run;
        run += (int)cnt_priv[(size_t)b * n + d];
    }
}

// ---- Kernel 7: bucket fill, zero device atomics ----
// slot = curb[b][dst] + (LDS-local rank within chunk b for this dst)
__global__ __launch_bounds__(256) void k_fill_lds(
    const float* __restrict__ ew, const int* __restrict__ src,
    const int* __restrict__ dst, const float* __restrict__ dis,
    const int* __restrict__ curb, int* __restrict__ esrc,
    float* __restrict__ ewgt, int E, int n, int ech, int rs) {

    __shared__ unsigned int curL[RSF_MAX];

    const int b = blockIdx.x & (NB - 1);
    const int r = blockIdx.x >> 7;
    const int base = r * rs;
    const int rse  = min(rs, n - base);

    for (int i = threadIdx.x; i < rse; i += 256) curL[i] = 0u;
    __syncthreads();

    const int e0 = b * ech, e1 = min(e0 + ech, E);
    for (int e = e0 + (int)threadIdx.x; e < e1; e += 256) {
        int d = dst[e];
        unsigned int rd_ = (unsigned int)(d - base);
        if (rd_ < (unsigned int)rse) {
            int s = src[e];
            float w = -dis[s] * ew[e] * dis[d];
            int local = (int)atomicAdd(&curL[rd_], 1u);
            int p = curb[(size_t)b * n + d] + local;
            esrc[p] = s;
            ewgt[p] = w;
        }
    }
}

// ---- Kernel 8: gather (bf16 rows) ----
__global__ __launch_bounds__(256) void k_gather_bf(
    const unsigned int* __restrict__ xw, const unsigned int* __restrict__ hw,
    const int* __restrict__ off, const int* __restrict__ esrc,
    const float* __restrict__ ewgt, const int* __restrict__ hflag,
    unsigned int* __restrict__ txw, unsigned int* __restrict__ thw, int n) {

    int d    = blockIdx.x * 4 + (threadIdx.x >> 6);
    int lane = threadIdx.x & 63;
    if (d >= n) return;
    const bool hasH = (*hflag) != 0;

    int p0 = off[d], p1 = off[d + 1];
    float ax0 = 0.f, ax1 = 0.f, ah0 = 0.f, ah1 = 0.f;
    int p = p0;

    if (hasH) {
        for (; p + 1 < p1; p += 2) {
            int   s0 = esrc[p],  s1 = esrc[p + 1];
            float w0 = ewgt[p],  w1 = ewgt[p + 1];
            unsigned int u0 = xw[(size_t)s0 * 64 + lane];
            unsigned int u1 = xw[(size_t)s1 * 64 + lane];
            unsigned int v0 = hw[(size_t)s0 * 64 + lane];
            unsigned int v1 = hw[(size_t)s1 * 64 + lane];
            ax0 = fmaf(w0, bflo(u0), ax0); ax1 = fmaf(w0, bfhi(u0), ax1);
            ah0 = fmaf(w0, bflo(v0), ah0); ah1 = fmaf(w0, bfhi(v0), ah1);
            ax0 = fmaf(w1, bflo(u1), ax0); ax1 = fmaf(w1, bfhi(u1), ax1);
            ah0 = fmaf(w1, bflo(v1), ah0); ah1 = fmaf(w1, bfhi(v1), ah1);
        }
        if (p < p1) {
            int s = esrc[p]; float w = ewgt[p];
            unsigned int u = xw[(size_t)s * 64 + lane];
            unsigned int v = hw[(size_t)s * 64 + lane];
            ax0 = fmaf(w, bflo(u), ax0); ax1 = fmaf(w, bfhi(u), ax1);
            ah0 = fmaf(w, bflo(v), ah0); ah1 = fmaf(w, bfhi(v), ah1);
        }
        txw[(size_t)d * 64 + lane] = pack2bf(ax0, ax1);
        thw[(size_t)d * 64 + lane] = pack2bf(ah0, ah1);
    } else {
        for (; p + 1 < p1; p += 2) {
            int   s0 = esrc[p],  s1 = esrc[p + 1];
            float w0 = ewgt[p],  w1 = ewgt[p + 1];
            unsigned int u0 = xw[(size_t)s0 * 64 + lane];
            unsigned int u1 = xw[(size_t)s1 * 64 + lane];
            ax0 = fmaf(w0, bflo(u0), ax0); ax1 = fmaf(w0, bfhi(u0), ax1);
            ax0 = fmaf(w1, bflo(u1), ax0); ax1 = fmaf(w1, bfhi(u1), ax1);
        }
        if (p < p1) {
            int s = esrc[p]; float w = ewgt[p];
            unsigned int u = xw[(size_t)s * 64 + lane];
            ax0 = fmaf(w, bflo(u), ax0); ax1 = fmaf(w, bfhi(u), ax1);
        }
        txw[(size_t)d * 64 + lane] = pack2bf(ax0, ax1);
    }
}

// ---- Kernel 9: pack A = [x|tx|h|th] (bf16 rows) into fragment order ----
__global__ __launch_bounds__(256) void k_pack_a(
    const unsigned short* __restrict__ xbf,  const unsigned short* __restrict__ txbf,
    const unsigned short* __restrict__ hbf,  const unsigned short* __restrict__ thbf,
    const int* __restrict__ hflag,
    unsigned short* __restrict__ Abf, int n, int nfrag) {

    int frag = blockIdx.x * 4 + (threadIdx.x >> 6);
    if (frag >= nfrag) return;
    int lane = threadIdx.x & 63;
    int rb = frag >> 4, kb = frag & 15;
    if (kb >= 8 && *hflag == 0) return;

    int r  = rb * 16 + (lane & 15);
    int k0 = kb * 32 + (lane >> 4) * 8;
    const unsigned short* srcp = (kb < 4) ? xbf : (kb < 8) ? txbf : (kb < 12) ? hbf : thbf;
    int col = k0 & (FD - 1);

    uint4 v = make_uint4(0u, 0u, 0u, 0u);
    if (r < n) v = *reinterpret_cast<const uint4*>(srcp + (size_t)r * FD + col);
    *reinterpret_cast<uint4*>(Abf + (size_t)frag * 512 + lane * 8) = v;
}

// ---- Kernel 10: pack Wcat into B-fragment order ----
__global__ void k_pack_w(const float* __restrict__ Wx, const float* __restrict__ Wh,
                         unsigned short* __restrict__ Wbf) {
    int frag = blockIdx.x * 4 + (threadIdx.x >> 6);   // 0..511
    int lane = threadIdx.x & 63;
    int cb = frag >> 4, kb = frag & 15;
    int col = cb * 16 + (lane & 15);
    int k0  = kb * 32 + (lane >> 4) * 8;

    int sel  = k0 >> 7;
    int g    = col >> 7;
    int j    = col & (FD - 1);
    const float* Wb = (sel < 2) ? Wx : Wh;
    const float* p = Wb + (((size_t)g * 2 + (sel & 1)) * FD + (k0 & (FD - 1))) * FD + j;

    unsigned short outv[8];
    #pragma unroll
    for (int i = 0; i < 8; ++i) outv[i] = f2bf(p[(size_t)i * FD]);

    *reinterpret_cast<uint4*>(Wbf + (size_t)frag * 512 + lane * 8) =
        *reinterpret_cast<uint4*>(outv);
}

// ---- Kernel 11: MFMA GEMM ----
__global__ __launch_bounds__(256) void k_gemm_mfma(
    const unsigned short* __restrict__ Abf, const unsigned short* __restrict__ Wbf,
    const int* __restrict__ hflag,
    unsigned short* __restrict__ gates, int n) {

    int wg   = blockIdx.x * 4 + (threadIdx.x >> 6);
    int lane = threadIdx.x & 63;
    int rt = wg >> 3;
    int ct = wg & 7;
    const int kbmax = (*hflag) ? 16 : 8;

    f32x4 acc[4][4];
    #pragma unroll
    for (int mi = 0; mi < 4; ++mi)
        #pragma unroll
        for (int nj = 0; nj < 4; ++nj)
            acc[mi][nj] = (f32x4)0.0f;

    const size_t aoff = ((size_t)(rt * 4) * 16) * 512 + lane * 8;
    const size_t boff = ((size_t)(ct * 4) * 16) * 512 + lane * 8;

    for (int kb = 0; kb < kbmax; ++kb) {
        bf16x8 a[4], b[4];
        #pragma unroll
        for (int mi = 0; mi < 4; ++mi)
            a[mi] = *reinterpret_cast<const bf16x8*>(Abf + aoff + (size_t)(mi * 16 + kb) * 512);
        #pragma unroll
        for (int nj = 0; nj < 4; ++nj)
            b[nj] = *reinterpret_cast<const bf16x8*>(Wbf + boff + (size_t)(nj * 16 + kb) * 512);
        #pragma unroll
        for (int mi = 0; mi < 4; ++mi)
            #pragma unroll
            for (int nj = 0; nj < 4; ++nj)
                acc[mi][nj] = __builtin_amdgcn_mfma_f32_16x16x32_bf16(
                                  a[mi], b[nj], acc[mi][nj], 0, 0, 0);
    }

    const int r0 = rt * 64, c0 = ct * 64;
    #pragma unroll
    for (int mi = 0; mi < 4; ++mi) {
        #pragma unroll
        for (int q = 0; q < 4; ++q) {
            int r = r0 + mi * 16 + (lane >> 4) * 4 + q;
            if (r < n) {
                #pragma unroll
                for (int nj = 0; nj < 4; ++nj) {
                    int cc = c0 + nj * 16 + (lane & 15);
                    gates[(size_t)r * 512 + cc] = f2bf(acc[mi][nj][q]);
                }
            }
        }
    }
}

// ---- Kernel 12: LSTM gate combine + write outputs ----
__global__ void k_combine(const unsigned short* __restrict__ gates,
                          const float* __restrict__ c,
                          const float* __restrict__ b, const float* __restrict__ wc,
                          float* __restrict__ out, int n) {
    int idx = blockIdx.x * blockDim.x + threadIdx.x;
    if (idx >= n * FD) return;
    int nr = idx >> 7, j = idx & (FD - 1);
    const unsigned short* grow = gates + (size_t)nr * (GATES * FD);
    float cv = c[idx];

    float gi = bf2f(grow[0 * FD + j]) + wc[0 * FD + j] * cv + b[0 * FD + j];
    float gf = bf2f(grow[1 * FD + j]) + wc[1 * FD + j] * cv + b[1 * FD + j];
    float gg = bf2f(grow[2 * FD + j]) + b[2 * FD + j];

    float iv = sigmoidf_(gi);
    float fv = sigmoidf_(gf);
    float cn = fv * cv + iv * tanhf(gg);

    float go = bf2f(grow[3 * FD + j]) + wc[2 * FD + j] * cn + b[3 * FD + j];
    float ov = sigmoidf_(go);
    float hn = ov * tanhf(cn);

    int NH = n * FD;
    out[idx]          = hn;
    out[NH + idx]     = hn;
    out[2 * NH + idx] = cn;
}

extern "C" void kernel_launch(void* const* d_in, const int* in_sizes, int n_in,
                              void* d_out, int out_size, void* d_ws, size_t ws_size,
                              hipStream_t stream) {
    const float* x   = (const float*)d_in[0];
    const float* ew  = (const float*)d_in[1];
    const float* h   = (const float*)d_in[2];
    const float* c   = (const float*)d_in[3];
    const float* Wx  = (const float*)d_in[4];
    const float* Wh  = (const float*)d_in[5];
    const float* b   = (const float*)d_in[6];
    const float* wc  = (const float*)d_in[7];
    const int*   src = (const int*)d_in[8];
    const int*   dst = (const int*)d_in[9];

    const int n = in_sizes[0] / FD;   // 20000
    const int E = in_sizes[1];        // 640000

    const int Mpad  = (n + 63) & ~63;
    const int nfrag = (Mpad / 16) * 16;
    const int ech   = (E + NB - 1) / NB;          // 5000
    const int rsh   = (n + NRH - 1) / NRH;        // 5000  (<= RSH_MAX)
    const int rsf   = (n + NRF - 1) / NRF;        // 10000 (<= RSF_MAX)

    // ---- workspace layout ----
    float* dis   = (float*)d_ws;                          // n
    int*   cnt   = (int*)(dis + n);                       // n
    int*   off   = cnt + n;                               // n+4
    int*   hflag = off + n + 4;                           // 4
    int*   esrc  = hflag + 4;                             // E
    float* ewgt  = (float*)(esrc + E);                    // E
    unsigned short* txbf = (unsigned short*)(ewgt + E);   // n*FD bf16
    unsigned short* thbf = txbf + (size_t)n * FD;         // n*FD
    unsigned short* xbf  = thbf + (size_t)n * FD;         // n*FD
    unsigned short* hbf  = xbf + (size_t)n * FD;          // n*FD
    unsigned short* gates= hbf + (size_t)n * FD;          // n*512
    unsigned short* Abf  = gates + (size_t)n * 512;       // Mpad*512
    unsigned short* Wbf  = Abf + (size_t)Mpad * 512;      // 512*512

    // aliases (consumed before their host regions are written):
    float*          deg_priv = (float*)gates;                       // NB*n f32  (15.4MB <= 20.5MB)
    unsigned short* cnt_priv = (unsigned short*)(deg_priv + (size_t)NB * n); // NB*n u16
    int*            curb     = (int*)Abf;                           // NB*n i32  (10.2MB <= 20.5MB)

    hipMemsetAsync(hflag, 0, 4, stream);

    k_flag<<<(n * FD / 4 + 255) / 256, 256, 0, stream>>>((const float4*)h, n * FD / 4, hflag);
    k_cvt<<<(n * FD / 8 + 255) / 256, 256, 0, stream>>>(x, h, xbf, hbf, hflag, n * FD / 8);

    k_hist_lds<<<NRH * NB, 256, 0, stream>>>(ew, src, dst, deg_priv, cnt_priv, E, n, ech, rsh);
    k_prep<<<(n + 255) / 256, 256, 0, stream>>>(deg_priv, cnt_priv, dis, cnt, n);
    k_scan<<<1, 1024, 0, stream>>>(cnt, off, n);
    k_colscan<<<(n + 255) / 256, 256, 0, stream>>>(cnt_priv, off, curb, n);
    k_fill_lds<<<NRF * NB, 256, 0, stream>>>(ew, src, dst, dis, curb, esrc, ewgt, E, n, ech, rsf);

    k_gather_bf<<<(n + 3) / 4, 256, 0, stream>>>(
        (const unsigned int*)xbf, (const unsigned int*)hbf, off, esrc, ewgt, hflag,
        (unsigned int*)txbf, (unsigned int*)thbf, n);

    k_pack_w<<<512 / 4, 256, 0, stream>>>(Wx, Wh, Wbf);
    k_pack_a<<<(nfrag + 3) / 4, 256, 0, stream>>>(xbf, txbf, hbf, thbf, hflag, Abf, n, nfrag);

    const int nwaves = (Mpad / 64) * 8;
    k_gemm_mfma<<<nwaves / 4, 256, 0, stream>>>(Abf, Wbf, hflag, gates, n);

    k_combine<<<(n * FD + 255) / 256, 256, 0, stream>>>(gates, c, b, wc, (float*)d_out, n);
}

// Round 7
// 155.336 us; speedup vs baseline: 4.6437x; 1.1240x over previous
//
#include <hip/hip_runtime.h>
#include <math.h>

#define FD 128
#define GATES 4
#define NB  128            // edge chunks (per-chunk private histograms)
#define NRH 2              // node ranges for hist (LDS = rs*(4+4) B)
#define RSH_MAX 10048      // max nodes per hist range  (80.4 KB LDS)
#define RSF_MAX 20032      // fill: whole node range    (80.1 KB LDS)

typedef __attribute__((ext_vector_type(8))) short bf16x8;
typedef __attribute__((ext_vector_type(4))) float f32x4;

__device__ __forceinline__ float sigmoidf_(float v) {
    return 1.0f / (1.0f + expf(-v));
}

__device__ __forceinline__ unsigned short f2bf(float f) {
    unsigned int u = __builtin_bit_cast(unsigned int, f);
    u += 0x7fffu + ((u >> 16) & 1u);           // RNE (finite values)
    return (unsigned short)(u >> 16);
}
__device__ __forceinline__ float bf2f(unsigned short s) {
    unsigned int u = ((unsigned int)s) << 16;
    return __builtin_bit_cast(float, u);
}
__device__ __forceinline__ float bflo(unsigned int u) {
    return __builtin_bit_cast(float, u << 16);
}
__device__ __forceinline__ float bfhi(unsigned int u) {
    return __builtin_bit_cast(float, u & 0xffff0000u);
}
__device__ __forceinline__ unsigned int pack2bf(float lo, float hi) {
    return (unsigned int)f2bf(lo) | ((unsigned int)f2bf(hi) << 16);
}

// ---- Kernel 1: LDS-private histogram over (chunk b, node-range r) ----
__global__ __launch_bounds__(256) void k_hist_lds(
    const float* __restrict__ ew, const int* __restrict__ src,
    const int* __restrict__ dst,
    float* __restrict__ deg_priv, unsigned short* __restrict__ cnt_priv,
    int E, int n, int ech, int rs) {

    __shared__ float        degL[RSH_MAX];
    __shared__ unsigned int cntL[RSH_MAX];

    const int b = blockIdx.x & (NB - 1);
    const int r = blockIdx.x >> 7;            // NB==128
    const int base = r * rs;
    const int rse  = min(rs, n - base);

    for (int i = threadIdx.x; i < rse; i += 256) { degL[i] = 0.f; cntL[i] = 0u; }
    __syncthreads();

    const int e0 = b * ech, e1 = min(e0 + ech, E);
    for (int e = e0 + (int)threadIdx.x; e < e1; e += 256) {
        int s = src[e], d = dst[e];
        unsigned int rs_ = (unsigned int)(s - base);
        unsigned int rd_ = (unsigned int)(d - base);
        if (rs_ < (unsigned int)rse) atomicAdd(&degL[rs_], ew[e]);
        if (rd_ < (unsigned int)rse) atomicAdd(&cntL[rd_], 1u);
    }
    __syncthreads();

    float*          dp = deg_priv + (size_t)b * n + base;
    unsigned short* cp = cnt_priv + (size_t)b * n + base;
    for (int i = threadIdx.x; i < rse; i += 256) {
        dp[i] = degL[i];
        cp[i] = (unsigned short)cntL[i];
    }
}

// ---- Kernel 2: fold copies: dis = rsqrt(sum deg), cnt = sum cnt ----
__global__ void k_prep(const float* __restrict__ deg_priv,
                       const unsigned short* __restrict__ cnt_priv,
                       float* __restrict__ dis, int* __restrict__ cnt, int n) {
    int d = blockIdx.x * blockDim.x + threadIdx.x;
    if (d >= n) return;
    float s = 0.f; int ct = 0;
    #pragma unroll 4
    for (int b = 0; b < NB; ++b) {
        s  += deg_priv[(size_t)b * n + d];
        ct += (int)cnt_priv[(size_t)b * n + d];
    }
    dis[d] = (s > 0.0f) ? rsqrtf(fmaxf(s, 1e-12f)) : 0.0f;
    cnt[d] = ct;
}

// ---- Kernel 3: h-nonzero flag ----
__global__ void k_flag(const float4* __restrict__ h4, int n4, int* __restrict__ flag) {
    int i = blockIdx.x * blockDim.x + threadIdx.x;
    bool nz = false;
    if (i < n4) {
        float4 v = h4[i];
        nz = (v.x != 0.f) | (v.y != 0.f) | (v.z != 0.f) | (v.w != 0.f);
    }
    unsigned long long m = __ballot(nz);
    if ((threadIdx.x & 63) == 0 && m) atomicOr(flag, 1);
}

// ---- Kernel 4: convert x (always) and h (if flag) to bf16 rows ----
__global__ void k_cvt(const float* __restrict__ x, const float* __restrict__ h,
                      unsigned short* __restrict__ xbf, unsigned short* __restrict__ hbf,
                      const int* __restrict__ hflag, int n8) {
    int i = blockIdx.x * blockDim.x + threadIdx.x;
    if (i >= n8) return;
    const float4* xp = reinterpret_cast<const float4*>(x) + (size_t)i * 2;
    float4 a = xp[0], bq = xp[1];
    uint4 o;
    o.x = pack2bf(a.x, a.y);  o.y = pack2bf(a.z, a.w);
    o.z = pack2bf(bq.x, bq.y); o.w = pack2bf(bq.z, bq.w);
    reinterpret_cast<uint4*>(xbf)[i] = o;
    if (*hflag) {
        const float4* hp = reinterpret_cast<const float4*>(h) + (size_t)i * 2;
        float4 cq = hp[0], dq = hp[1];
        uint4 o2;
        o2.x = pack2bf(cq.x, cq.y); o2.y = pack2bf(cq.z, cq.w);
        o2.z = pack2bf(dq.x, dq.y); o2.w = pack2bf(dq.z, dq.w);
        reinterpret_cast<uint4*>(hbf)[i] = o2;
    }
}

// ---- Kernel 5: exclusive scan of cnt -> off (single block) ----
__global__ __launch_bounds__(1024) void k_scan(const int* __restrict__ cnt,
                                               int* __restrict__ off, int n) {
    __shared__ int warp_sums[16];
    __shared__ int base_sh;
    if (threadIdx.x == 0) base_sh = 0;
    __syncthreads();

    const int lane = threadIdx.x & 63;
    const int wid  = threadIdx.x >> 6;

    for (int start = 0; start < n; start += 1024) {
        int i = start + (int)threadIdx.x;
        int v = (i < n) ? cnt[i] : 0;
        int s = v;
        #pragma unroll
        for (int d = 1; d < 64; d <<= 1) {
            int t = __shfl_up(s, d);
            if (lane >= d) s += t;
        }
        if (lane == 63) warp_sums[wid] = s;
        __syncthreads();
        if (wid == 0 && lane < 16) {
            int ws = warp_sums[lane];
            #pragma unroll
            for (int d = 1; d < 16; d <<= 1) {
                int t = __shfl_up(ws, d);
                if (lane >= d) ws += t;
            }
            warp_sums[lane] = ws;
        }
        __syncthreads();
        int wbase = (wid > 0) ? warp_sums[wid - 1] : 0;
        int excl  = base_sh + wbase + (s - v);
        if (i < n) off[i] = excl;
        int chunk_total = warp_sums[15];
        __syncthreads();
        if (threadIdx.x == 0) base_sh += chunk_total;
        __syncthreads();
    }
    if (threadIdx.x == 0) off[n] = base_sh;
}

// ---- Kernel 6: column scan: curb[b][d] = off[d] + prefix_b(cnt_priv) ----
__global__ void k_colscan(const unsigned short* __restrict__ cnt_priv,
                          const int* __restrict__ off,
                          int* __restrict__ curb, int n) {
    int d = blockIdx.x * blockDim.x + threadIdx.x;
    if (d >= n) return;
    int run = off[d];
    #pragma unroll 4
    for (int b = 0; b < NB; ++b) {
        curb[(size_t)b * n + d] = run;
        run += (int)cnt_priv[(size_t)b * n + d];
    }
}

// ---- Kernel 7: bucket fill, zero device atomics, packed (src,w) ----
__global__ __launch_bounds__(256) void k_fill_lds(
    const float* __restrict__ ew, const int* __restrict__ src,
    const int* __restrict__ dst, const float* __restrict__ dis,
    const int* __restrict__ curb, int2* __restrict__ epk,
    int E, int n, int ech) {

    __shared__ unsigned int curL[RSF_MAX];

    const int b = blockIdx.x;      // single node range covers all n
    for (int i = threadIdx.x; i < n; i += 256) curL[i] = 0u;
    __syncthreads();

    const int e0 = b * ech, e1 = min(e0 + ech, E);
    for (int e = e0 + (int)threadIdx.x; e < e1; e += 256) {
        int d = dst[e];
        int s = src[e];
        float w = -dis[s] * ew[e] * dis[d];
        int local = (int)atomicAdd(&curL[d], 1u);
        int p = curb[(size_t)b * n + d] + local;
        epk[p] = make_int2(s, __builtin_bit_cast(int, w));
    }
}

// ---- Kernel 8: gather (bf16 rows), shfl-broadcast + unroll-4 ----
__global__ __launch_bounds__(256) void k_gather_bf(
    const unsigned int* __restrict__ xw, const unsigned int* __restrict__ hw,
    const int* __restrict__ off, const int2* __restrict__ epk,
    const int* __restrict__ hflag,
    unsigned int* __restrict__ txw, unsigned int* __restrict__ thw, int n) {

    int d    = blockIdx.x * 4 + (threadIdx.x >> 6);
    int lane = threadIdx.x & 63;
    if (d >= n) return;
    const bool hasH = (*hflag) != 0;

    int p0 = off[d], p1 = off[d + 1];
    float ax0 = 0.f, ax1 = 0.f, ah0 = 0.f, ah1 = 0.f;

    if (!hasH) {
        for (int base = p0; base < p1; base += 64) {
            int cnt = min(64, p1 - base);
            int2 my = make_int2(0, 0);
            if (lane < cnt) my = epk[base + lane];
            int   sm = my.x;
            float wm = __builtin_bit_cast(float, my.y);
            int k = 0;
            for (; k + 4 <= cnt; k += 4) {
                int   s0 = __shfl(sm, k),     s1 = __shfl(sm, k + 1);
                int   s2 = __shfl(sm, k + 2), s3 = __shfl(sm, k + 3);
                float w0 = __shfl(wm, k),     w1 = __shfl(wm, k + 1);
                float w2 = __shfl(wm, k + 2), w3 = __shfl(wm, k + 3);
                unsigned int u0 = xw[s0 * 64 + lane];
                unsigned int u1 = xw[s1 * 64 + lane];
                unsigned int u2 = xw[s2 * 64 + lane];
                unsigned int u3 = xw[s3 * 64 + lane];
                ax0 = fmaf(w0, bflo(u0), ax0); ax1 = fmaf(w0, bfhi(u0), ax1);
                ax0 = fmaf(w1, bflo(u1), ax0); ax1 = fmaf(w1, bfhi(u1), ax1);
                ax0 = fmaf(w2, bflo(u2), ax0); ax1 = fmaf(w2, bfhi(u2), ax1);
                ax0 = fmaf(w3, bflo(u3), ax0); ax1 = fmaf(w3, bfhi(u3), ax1);
            }
            for (; k < cnt; ++k) {
                int s = __shfl(sm, k);
                float w = __shfl(wm, k);
                unsigned int u = xw[s * 64 + lane];
                ax0 = fmaf(w, bflo(u), ax0); ax1 = fmaf(w, bfhi(u), ax1);
            }
        }
        txw[(size_t)d * 64 + lane] = pack2bf(ax0, ax1);
    } else {
        for (int base = p0; base < p1; base += 64) {
            int cnt = min(64, p1 - base);
            int2 my = make_int2(0, 0);
            if (lane < cnt) my = epk[base + lane];
            int   sm = my.x;
            float wm = __builtin_bit_cast(float, my.y);
            int k = 0;
            for (; k + 2 <= cnt; k += 2) {
                int   s0 = __shfl(sm, k), s1 = __shfl(sm, k + 1);
                float w0 = __shfl(wm, k), w1 = __shfl(wm, k + 1);
                unsigned int u0 = xw[s0 * 64 + lane];
                unsigned int v0 = hw[s0 * 64 + lane];
                unsigned int u1 = xw[s1 * 64 + lane];
                unsigned int v1 = hw[s1 * 64 + lane];
                ax0 = fmaf(w0, bflo(u0), ax0); ax1 = fmaf(w0, bfhi(u0), ax1);
                ah0 = fmaf(w0, bflo(v0), ah0); ah1 = fmaf(w0, bfhi(v0), ah1);
                ax0 = fmaf(w1, bflo(u1), ax0); ax1 = fmaf(w1, bfhi(u1), ax1);
                ah0 = fmaf(w1, bflo(v1), ah0); ah1 = fmaf(w1, bfhi(v1), ah1);
            }
            for (; k < cnt; ++k) {
                int s = __shfl(sm, k);
                float w = __shfl(wm, k);
                unsigned int u = xw[s * 64 + lane];
                unsigned int v = hw[s * 64 + lane];
                ax0 = fmaf(w, bflo(u), ax0); ax1 = fmaf(w, bfhi(u), ax1);
                ah0 = fmaf(w, bflo(v), ah0); ah1 = fmaf(w, bfhi(v), ah1);
            }
        }
        txw[(size_t)d * 64 + lane] = pack2bf(ax0, ax1);
        thw[(size_t)d * 64 + lane] = pack2bf(ah0, ah1);
    }
}

// ---- Kernel 9: pack A = [x|tx|h|th] (bf16 rows) into fragment order ----
__global__ __launch_bounds__(256) void k_pack_a(
    const unsigned short* __restrict__ xbf,  const unsigned short* __restrict__ txbf,
    const unsigned short* __restrict__ hbf,  const unsigned short* __restrict__ thbf,
    const int* __restrict__ hflag,
    unsigned short* __restrict__ Abf, int n, int nfrag) {

    int frag = blockIdx.x * 4 + (threadIdx.x >> 6);
    if (frag >= nfrag) return;
    int lane = threadIdx.x & 63;
    int rb = frag >> 4, kb = frag & 15;
    if (kb >= 8 && *hflag == 0) return;

    int r  = rb * 16 + (lane & 15);
    int k0 = kb * 32 + (lane >> 4) * 8;
    const unsigned short* srcp = (kb < 4) ? xbf : (kb < 8) ? txbf : (kb < 12) ? hbf : thbf;
    int col = k0 & (FD - 1);

    uint4 v = make_uint4(0u, 0u, 0u, 0u);
    if (r < n) v = *reinterpret_cast<const uint4*>(srcp + (size_t)r * FD + col);
    *reinterpret_cast<uint4*>(Abf + (size_t)frag * 512 + lane * 8) = v;
}

// ---- Kernel 10: pack Wcat into B-fragment order ----
__global__ void k_pack_w(const float* __restrict__ Wx, const float* __restrict__ Wh,
                         unsigned short* __restrict__ Wbf) {
    int frag = blockIdx.x * 4 + (threadIdx.x >> 6);   // 0..511
    int lane = threadIdx.x & 63;
    int cb = frag >> 4, kb = frag & 15;
    int col = cb * 16 + (lane & 15);
    int k0  = kb * 32 + (lane >> 4) * 8;

    int sel  = k0 >> 7;
    int g    = col >> 7;
    int j    = col & (FD - 1);
    const float* Wb = (sel < 2) ? Wx : Wh;
    const float* p = Wb + (((size_t)g * 2 + (sel & 1)) * FD + (k0 & (FD - 1))) * FD + j;

    unsigned short outv[8];
    #pragma unroll
    for (int i = 0; i < 8; ++i) outv[i] = f2bf(p[(size_t)i * FD]);

    *reinterpret_cast<uint4*>(Wbf + (size_t)frag * 512 + lane * 8) =
        *reinterpret_cast<uint4*>(outv);
}

// ---- Kernel 11: MFMA GEMM ----
__global__ __launch_bounds__(256) void k_gemm_mfma(
    const unsigned short* __restrict__ Abf, const unsigned short* __restrict__ Wbf,
    const int* __restrict__ hflag,
    unsigned short* __restrict__ gates, int n) {

    int wg   = blockIdx.x * 4 + (threadIdx.x >> 6);
    int lane = threadIdx.x & 63;
    int rt = wg >> 3;
    int ct = wg & 7;
    const int kbmax = (*hflag) ? 16 : 8;

    f32x4 acc[4][4];
    #pragma unroll
    for (int mi = 0; mi < 4; ++mi)
        #pragma unroll
        for (int nj = 0; nj < 4; ++nj)
            acc[mi][nj] = (f32x4)0.0f;

    const size_t aoff = ((size_t)(rt * 4) * 16) * 512 + lane * 8;
    const size_t boff = ((size_t)(ct * 4) * 16) * 512 + lane * 8;

    for (int kb = 0; kb < kbmax; ++kb) {
        bf16x8 a[4], b[4];
        #pragma unroll
        for (int mi = 0; mi < 4; ++mi)
            a[mi] = *reinterpret_cast<const bf16x8*>(Abf + aoff + (size_t)(mi * 16 + kb) * 512);
        #pragma unroll
        for (int nj = 0; nj < 4; ++nj)
            b[nj] = *reinterpret_cast<const bf16x8*>(Wbf + boff + (size_t)(nj * 16 + kb) * 512);
        #pragma unroll
        for (int mi = 0; mi < 4; ++mi)
            #pragma unroll
            for (int nj = 0; nj < 4; ++nj)
                acc[mi][nj] = __builtin_amdgcn_mfma_f32_16x16x32_bf16(
                                  a[mi], b[nj], acc[mi][nj], 0, 0, 0);
    }

    const int r0 = rt * 64, c0 = ct * 64;
    #pragma unroll
    for (int mi = 0; mi < 4; ++mi) {
        #pragma unroll
        for (int q = 0; q < 4; ++q) {
            int r = r0 + mi * 16 + (lane >> 4) * 4 + q;
            if (r < n) {
                #pragma unroll
                for (int nj = 0; nj < 4; ++nj) {
                    int cc = c0 + nj * 16 + (lane & 15);
                    gates[(size_t)r * 512 + cc] = f2bf(acc[mi][nj][q]);
                }
            }
        }
    }
}

// ---- Kernel 12: LSTM gate combine + write outputs ----
__global__ void k_combine(const unsigned short* __restrict__ gates,
                          const float* __restrict__ c,
                          const float* __restrict__ b, const float* __restrict__ wc,
                          float* __restrict__ out, int n) {
    int idx = blockIdx.x * blockDim.x + threadIdx.x;
    if (idx >= n * FD) return;
    int nr = idx >> 7, j = idx & (FD - 1);
    const unsigned short* grow = gates + (size_t)nr * (GATES * FD);
    float cv = c[idx];

    float gi = bf2f(grow[0 * FD + j]) + wc[0 * FD + j] * cv + b[0 * FD + j];
    float gf = bf2f(grow[1 * FD + j]) + wc[1 * FD + j] * cv + b[1 * FD + j];
    float gg = bf2f(grow[2 * FD + j]) + b[2 * FD + j];

    float iv = sigmoidf_(gi);
    float fv = sigmoidf_(gf);
    float cn = fv * cv + iv * tanhf(gg);

    float go = bf2f(grow[3 * FD + j]) + wc[2 * FD + j] * cn + b[3 * FD + j];
    float ov = sigmoidf_(go);
    float hn = ov * tanhf(cn);

    int NH = n * FD;
    out[idx]          = hn;
    out[NH + idx]     = hn;
    out[2 * NH + idx] = cn;
}

extern "C" void kernel_launch(void* const* d_in, const int* in_sizes, int n_in,
                              void* d_out, int out_size, void* d_ws, size_t ws_size,
                              hipStream_t stream) {
    const float* x   = (const float*)d_in[0];
    const float* ew  = (const float*)d_in[1];
    const float* h   = (const float*)d_in[2];
    const float* c   = (const float*)d_in[3];
    const float* Wx  = (const float*)d_in[4];
    const float* Wh  = (const float*)d_in[5];
    const float* b   = (const float*)d_in[6];
    const float* wc  = (const float*)d_in[7];
    const int*   src = (const int*)d_in[8];
    const int*   dst = (const int*)d_in[9];

    const int n = in_sizes[0] / FD;   // 20000
    const int E = in_sizes[1];        // 640000

    const int Mpad  = (n + 63) & ~63;
    const int nfrag = (Mpad / 16) * 16;
    const int ech   = (E + NB - 1) / NB;          // 5000
    const int rsh   = (n + NRH - 1) / NRH;        // 10000 (<= RSH_MAX)

    // ---- workspace layout ----
    float* dis   = (float*)d_ws;                          // n
    int*   cnt   = (int*)(dis + n);                       // n
    int*   off   = cnt + n;                               // n+4
    int*   hflag = off + n + 4;                           // 4
    int2*  epk   = (int2*)(hflag + 4);                    // E (src,w) pairs
    unsigned short* txbf = (unsigned short*)(epk + E);    // n*FD bf16
    unsigned short* thbf = txbf + (size_t)n * FD;         // n*FD
    unsigned short* xbf  = thbf + (size_t)n * FD;         // n*FD
    unsigned short* hbf  = xbf + (size_t)n * FD;          // n*FD
    unsigned short* gates= hbf + (size_t)n * FD;          // n*512
    unsigned short* Abf  = gates + (size_t)n * 512;       // Mpad*512
    unsigned short* Wbf  = Abf + (size_t)Mpad * 512;      // 512*512

    // aliases (consumed before their host regions are written):
    float*          deg_priv = (float*)gates;                                // NB*n f32
    unsigned short* cnt_priv = (unsigned short*)(deg_priv + (size_t)NB * n); // NB*n u16
    int*            curb     = (int*)Abf;                                    // NB*n i32

    hipMemsetAsync(hflag, 0, 4, stream);

    k_flag<<<(n * FD / 4 + 255) / 256, 256, 0, stream>>>((const float4*)h, n * FD / 4, hflag);
    k_cvt<<<(n * FD / 8 + 255) / 256, 256, 0, stream>>>(x, h, xbf, hbf, hflag, n * FD / 8);

    k_hist_lds<<<NRH * NB, 256, 0, stream>>>(ew, src, dst, deg_priv, cnt_priv, E, n, ech, rsh);
    k_prep<<<(n + 255) / 256, 256, 0, stream>>>(deg_priv, cnt_priv, dis, cnt, n);
    k_scan<<<1, 1024, 0, stream>>>(cnt, off, n);
    k_colscan<<<(n + 255) / 256, 256, 0, stream>>>(cnt_priv, off, curb, n);
    k_fill_lds<<<NB, 256, 0, stream>>>(ew, src, dst, dis, curb, epk, E, n, ech);

    k_gather_bf<<<(n + 3) / 4, 256, 0, stream>>>(
        (const unsigned int*)xbf, (const unsigned int*)hbf, off, epk, hflag,
        (unsigned int*)txbf, (unsigned int*)thbf, n);

    k_pack_w<<<512 / 4, 256, 0, stream>>>(Wx, Wh, Wbf);
    k_pack_a<<<(nfrag + 3) / 4, 256, 0, stream>>>(xbf, txbf, hbf, thbf, hflag, Abf, n, nfrag);

    const int nwaves = (Mpad / 64) * 8;
    k_gemm_mfma<<<nwaves / 4, 256, 0, stream>>>(Abf, Wbf, hflag, gates, n);

    k_combine<<<(n * FD + 255) / 256, 256, 0, stream>>>(gates, c, b, wc, (float*)d_out, n);
}

// Round 8
// 142.095 us; speedup vs baseline: 5.0764x; 1.0932x over previous
//
#include <hip/hip_runtime.h>
#include <math.h>

#define FD 128
#define GATES 4
#define NB  128            // edge chunks (per-chunk private histograms)
#define NRH 2              // node ranges for hist
#define RSH_MAX 10048      // max nodes per hist range  (80.4 KB LDS)
#define RSF_MAX 20032      // fill: whole node range    (80.1 KB LDS)

typedef __attribute__((ext_vector_type(8))) short bf16x8;
typedef __attribute__((ext_vector_type(4))) float f32x4;

__device__ __forceinline__ float sigmoidf_(float v) {
    return 1.0f / (1.0f + expf(-v));
}

__device__ __forceinline__ unsigned short f2bf(float f) {
    unsigned int u = __builtin_bit_cast(unsigned int, f);
    u += 0x7fffu + ((u >> 16) & 1u);           // RNE (finite values)
    return (unsigned short)(u >> 16);
}
__device__ __forceinline__ float bf2f(unsigned short s) {
    unsigned int u = ((unsigned int)s) << 16;
    return __builtin_bit_cast(float, u);
}
__device__ __forceinline__ float bflo(unsigned int u) {
    return __builtin_bit_cast(float, u << 16);
}
__device__ __forceinline__ float bfhi(unsigned int u) {
    return __builtin_bit_cast(float, u & 0xffff0000u);
}
__device__ __forceinline__ unsigned int pack2bf(float lo, float hi) {
    return (unsigned int)f2bf(lo) | ((unsigned int)f2bf(hi) << 16);
}

// ---- Kernel 1: cvt x,h -> bf16 rows + A-fragments (kb 0-3, 8-11) + flag parts
// thread t: row r = t>>4, octet o = t&15 (cols 8o..8o+7). The octet IS one
// fragment uint4 slot: frag = (r>>4)*16 + kb, slot = ((r&15)+16*(o&3))*8.
__global__ __launch_bounds__(256) void k_cvt(
    const float* __restrict__ x, const float* __restrict__ h,
    unsigned int* __restrict__ xw, unsigned int* __restrict__ hw,
    unsigned short* __restrict__ Abf, int* __restrict__ flagpart, int n16) {

    int t = blockIdx.x * 256 + threadIdx.x;
    bool nz = false;
    if (t < n16) {
        int r = t >> 4, o = t & 15;
        int slot = ((r & 15) + 16 * (o & 3)) * 8;
        size_t fb = ((size_t)(r >> 4) * 16) * 512;

        const float4* xp = reinterpret_cast<const float4*>(x) + (size_t)t * 2;
        float4 a = xp[0], bq = xp[1];
        uint4 ox;
        ox.x = pack2bf(a.x, a.y);   ox.y = pack2bf(a.z, a.w);
        ox.z = pack2bf(bq.x, bq.y); ox.w = pack2bf(bq.z, bq.w);
        reinterpret_cast<uint4*>(xw)[t] = ox;
        *reinterpret_cast<uint4*>(Abf + fb + (size_t)(o >> 2) * 512 + slot) = ox;

        const float4* hp = reinterpret_cast<const float4*>(h) + (size_t)t * 2;
        float4 hc = hp[0], hd = hp[1];
        nz = (hc.x != 0.f) | (hc.y != 0.f) | (hc.z != 0.f) | (hc.w != 0.f) |
             (hd.x != 0.f) | (hd.y != 0.f) | (hd.z != 0.f) | (hd.w != 0.f);
        uint4 oh;
        oh.x = pack2bf(hc.x, hc.y); oh.y = pack2bf(hc.z, hc.w);
        oh.z = pack2bf(hd.x, hd.y); oh.w = pack2bf(hd.z, hd.w);
        reinterpret_cast<uint4*>(hw)[t] = oh;
        *reinterpret_cast<uint4*>(Abf + fb + (size_t)(8 + (o >> 2)) * 512 + slot) = oh;
    }
    __shared__ int fsh;
    if (threadIdx.x == 0) fsh = 0;
    __syncthreads();
    unsigned long long m = __ballot(nz);
    if ((threadIdx.x & 63) == 0 && m) atomicOr(&fsh, 1);
    __syncthreads();
    if (threadIdx.x == 0) flagpart[blockIdx.x] = fsh;
}

// ---- Kernel 2: LDS-private histogram over (chunk b, node-range r) ----
__global__ __launch_bounds__(512) void k_hist_lds(
    const float* __restrict__ ew, const int* __restrict__ src,
    const int* __restrict__ dst,
    float* __restrict__ deg_priv, unsigned short* __restrict__ cnt_priv,
    int E, int n, int ech, int rs) {

    __shared__ float        degL[RSH_MAX];
    __shared__ unsigned int cntL[RSH_MAX];

    const int b = blockIdx.x & (NB - 1);
    const int r = blockIdx.x >> 7;            // NB==128
    const int base = r * rs;
    const int rse  = min(rs, n - base);

    for (int i = threadIdx.x; i < rse; i += 512) { degL[i] = 0.f; cntL[i] = 0u; }
    __syncthreads();

    const int e0 = b * ech, e1 = min(e0 + ech, E);
    for (int e = e0 + (int)threadIdx.x; e < e1; e += 512) {
        int s = src[e], d = dst[e];
        unsigned int rs_ = (unsigned int)(s - base);
        unsigned int rd_ = (unsigned int)(d - base);
        if (rs_ < (unsigned int)rse) atomicAdd(&degL[rs_], ew[e]);
        if (rd_ < (unsigned int)rse) atomicAdd(&cntL[rd_], 1u);
    }
    __syncthreads();

    float*          dp = deg_priv + (size_t)b * n + base;
    unsigned short* cp = cnt_priv + (size_t)b * n + base;
    for (int i = threadIdx.x; i < rse; i += 512) {
        dp[i] = degL[i];
        cp[i] = (unsigned short)cntL[i];
    }
}

// ---- Kernel 3: fold copies: dis = rsqrt(sum deg), cnt = sum cnt ----
__global__ void k_prep(const float* __restrict__ deg_priv,
                       const unsigned short* __restrict__ cnt_priv,
                       float* __restrict__ dis, int* __restrict__ cnt, int n) {
    int d = blockIdx.x * blockDim.x + threadIdx.x;
    if (d >= n) return;
    float s = 0.f; int ct = 0;
    #pragma unroll 4
    for (int b = 0; b < NB; ++b) {
        s  += deg_priv[(size_t)b * n + d];
        ct += (int)cnt_priv[(size_t)b * n + d];
    }
    dis[d] = (s > 0.0f) ? rsqrtf(fmaxf(s, 1e-12f)) : 0.0f;
    cnt[d] = ct;
}

// ---- Kernel 4: flag-OR + exclusive scan of cnt -> off (single block) ----
__global__ __launch_bounds__(1024) void k_scan(const int* __restrict__ cnt,
                                               int* __restrict__ off,
                                               const int* __restrict__ flagpart,
                                               int* __restrict__ hflag,
                                               int n, int nfp) {
    __shared__ int warp_sums[16];
    __shared__ int base_sh;
    __shared__ int fsh;
    if (threadIdx.x == 0) { base_sh = 0; fsh = 0; }
    __syncthreads();

    int fl = 0;
    for (int i = threadIdx.x; i < nfp; i += 1024) fl |= flagpart[i];
    if (fl) atomicOr(&fsh, 1);
    __syncthreads();
    if (threadIdx.x == 0) hflag[0] = fsh;

    const int lane = threadIdx.x & 63;
    const int wid  = threadIdx.x >> 6;

    for (int start = 0; start < n; start += 1024) {
        int i = start + (int)threadIdx.x;
        int v = (i < n) ? cnt[i] : 0;
        int s = v;
        #pragma unroll
        for (int d = 1; d < 64; d <<= 1) {
            int t = __shfl_up(s, d);
            if (lane >= d) s += t;
        }
        if (lane == 63) warp_sums[wid] = s;
        __syncthreads();
        if (wid == 0 && lane < 16) {
            int ws = warp_sums[lane];
            #pragma unroll
            for (int d = 1; d < 16; d <<= 1) {
                int t = __shfl_up(ws, d);
                if (lane >= d) ws += t;
            }
            warp_sums[lane] = ws;
        }
        __syncthreads();
        int wbase = (wid > 0) ? warp_sums[wid - 1] : 0;
        int excl  = base_sh + wbase + (s - v);
        if (i < n) off[i] = excl;
        int chunk_total = warp_sums[15];
        __syncthreads();
        if (threadIdx.x == 0) base_sh += chunk_total;
        __syncthreads();
    }
    if (threadIdx.x == 0) off[n] = base_sh;
}

// ---- Kernel 5: column scan: curb[b][d] = off[d] + prefix_b(cnt_priv) ----
__global__ void k_colscan(const unsigned short* __restrict__ cnt_priv,
                          const int* __restrict__ off,
                          int* __restrict__ curb, int n) {
    int d = blockIdx.x * blockDim.x + threadIdx.x;
    if (d >= n) return;
    int run = off[d];
    #pragma unroll 4
    for (int b = 0; b < NB; ++b) {
        curb[(size_t)b * n + d] = run;
        run += (int)cnt_priv[(size_t)b * n + d];
    }
}

// ---- Kernel 6: bucket fill, zero device atomics, packed (src,w) ----
__global__ __launch_bounds__(512) void k_fill_lds(
    const float* __restrict__ ew, const int* __restrict__ src,
    const int* __restrict__ dst, const float* __restrict__ dis,
    const int* __restrict__ curb, int2* __restrict__ epk,
    int E, int n, int ech) {

    __shared__ unsigned int curL[RSF_MAX];

    const int b = blockIdx.x;      // single node range covers all n
    for (int i = threadIdx.x; i < n; i += 512) curL[i] = 0u;
    __syncthreads();

    const int e0 = b * ech, e1 = min(e0 + ech, E);
    for (int e = e0 + (int)threadIdx.x; e < e1; e += 512) {
        int d = dst[e];
        int s = src[e];
        float w = -dis[s] * ew[e] * dis[d];
        int local = (int)atomicAdd(&curL[d], 1u);
        int p = curb[(size_t)b * n + d] + local;
        epk[p] = make_int2(s, __builtin_bit_cast(int, w));
    }
}

// ---- Kernel 7: gather -> writes tx/th A-fragments (kb 4-7, 12-15) directly
// lane holds cols 2*lane, 2*lane+1 of row d:
//   frag = (d>>4)*16 + 4 + (lane>>4); uint slot = ((d&15)+16*((lane>>2)&3))*4 + (lane&3)
__global__ __launch_bounds__(256) void k_gather_bf(
    const unsigned int* __restrict__ xw, const unsigned int* __restrict__ hw,
    const int* __restrict__ off, const int2* __restrict__ epk,
    const int* __restrict__ hflag,
    unsigned short* __restrict__ Abf, int n) {

    int d    = blockIdx.x * 4 + (threadIdx.x >> 6);
    int lane = threadIdx.x & 63;
    if (d >= n) return;
    const bool hasH = (*hflag) != 0;

    int p0 = off[d], p1 = off[d + 1];
    float ax0 = 0.f, ax1 = 0.f, ah0 = 0.f, ah1 = 0.f;

    if (!hasH) {
        for (int base = p0; base < p1; base += 64) {
            int cnt = min(64, p1 - base);
            int2 my = make_int2(0, 0);
            if (lane < cnt) my = epk[base + lane];
            int   sm = my.x;
            float wm = __builtin_bit_cast(float, my.y);
            int k = 0;
            for (; k + 4 <= cnt; k += 4) {
                int   s0 = __shfl(sm, k),     s1 = __shfl(sm, k + 1);
                int   s2 = __shfl(sm, k + 2), s3 = __shfl(sm, k + 3);
                float w0 = __shfl(wm, k),     w1 = __shfl(wm, k + 1);
                float w2 = __shfl(wm, k + 2), w3 = __shfl(wm, k + 3);
                unsigned int u0 = xw[s0 * 64 + lane];
                unsigned int u1 = xw[s1 * 64 + lane];
                unsigned int u2 = xw[s2 * 64 + lane];
                unsigned int u3 = xw[s3 * 64 + lane];
                ax0 = fmaf(w0, bflo(u0), ax0); ax1 = fmaf(w0, bfhi(u0), ax1);
                ax0 = fmaf(w1, bflo(u1), ax0); ax1 = fmaf(w1, bfhi(u1), ax1);
                ax0 = fmaf(w2, bflo(u2), ax0); ax1 = fmaf(w2, bfhi(u2), ax1);
                ax0 = fmaf(w3, bflo(u3), ax0); ax1 = fmaf(w3, bfhi(u3), ax1);
            }
            for (; k < cnt; ++k) {
                int s = __shfl(sm, k);
                float w = __shfl(wm, k);
                unsigned int u = xw[s * 64 + lane];
                ax0 = fmaf(w, bflo(u), ax0); ax1 = fmaf(w, bfhi(u), ax1);
            }
        }
    } else {
        for (int base = p0; base < p1; base += 64) {
            int cnt = min(64, p1 - base);
            int2 my = make_int2(0, 0);
            if (lane < cnt) my = epk[base + lane];
            int   sm = my.x;
            float wm = __builtin_bit_cast(float, my.y);
            int k = 0;
            for (; k + 2 <= cnt; k += 2) {
                int   s0 = __shfl(sm, k), s1 = __shfl(sm, k + 1);
                float w0 = __shfl(wm, k), w1 = __shfl(wm, k + 1);
                unsigned int u0 = xw[s0 * 64 + lane];
                unsigned int v0 = hw[s0 * 64 + lane];
                unsigned int u1 = xw[s1 * 64 + lane];
                unsigned int v1 = hw[s1 * 64 + lane];
                ax0 = fmaf(w0, bflo(u0), ax0); ax1 = fmaf(w0, bfhi(u0), ax1);
                ah0 = fmaf(w0, bflo(v0), ah0); ah1 = fmaf(w0, bfhi(v0), ah1);
                ax0 = fmaf(w1, bflo(u1), ax0); ax1 = fmaf(w1, bfhi(u1), ax1);
                ah0 = fmaf(w1, bflo(v1), ah0); ah1 = fmaf(w1, bfhi(v1), ah1);
            }
            for (; k < cnt; ++k) {
                int s = __shfl(sm, k);
                float w = __shfl(wm, k);
                unsigned int u = xw[s * 64 + lane];
                unsigned int v = hw[s * 64 + lane];
                ax0 = fmaf(w, bflo(u), ax0); ax1 = fmaf(w, bfhi(u), ax1);
                ah0 = fmaf(w, bflo(v), ah0); ah1 = fmaf(w, bfhi(v), ah1);
            }
        }
    }

    unsigned int* Au = (unsigned int*)Abf;
    size_t fragT = (size_t)(d >> 4) * 16 + 4 + (lane >> 4);
    int slotu = ((d & 15) + 16 * ((lane >> 2) & 3)) * 4 + (lane & 3);
    Au[fragT * 256 + slotu] = pack2bf(ax0, ax1);
    if (hasH) Au[(fragT + 8) * 256 + slotu] = pack2bf(ah0, ah1);
}

// ---- Kernel 8: pack Wcat into B-fragment order ----
__global__ void k_pack_w(const float* __restrict__ Wx, const float* __restrict__ Wh,
                         unsigned short* __restrict__ Wbf) {
    int frag = blockIdx.x * 4 + (threadIdx.x >> 6);   // 0..511
    int lane = threadIdx.x & 63;
    int cb = frag >> 4, kb = frag & 15;
    int col = cb * 16 + (lane & 15);
    int k0  = kb * 32 + (lane >> 4) * 8;

    int sel  = k0 >> 7;
    int g    = col >> 7;
    int j    = col & (FD - 1);
    const float* Wb = (sel < 2) ? Wx : Wh;
    const float* p = Wb + (((size_t)g * 2 + (sel & 1)) * FD + (k0 & (FD - 1))) * FD + j;

    unsigned short outv[8];
    #pragma unroll
    for (int i = 0; i < 8; ++i) outv[i] = f2bf(p[(size_t)i * FD]);

    *reinterpret_cast<uint4*>(Wbf + (size_t)frag * 512 + lane * 8) =
        *reinterpret_cast<uint4*>(outv);
}

// ---- Kernel 9: MFMA GEMM ----
__global__ __launch_bounds__(256) void k_gemm_mfma(
    const unsigned short* __restrict__ Abf, const unsigned short* __restrict__ Wbf,
    const int* __restrict__ hflag,
    unsigned short* __restrict__ gates, int n) {

    int wg   = blockIdx.x * 4 + (threadIdx.x >> 6);
    int lane = threadIdx.x & 63;
    int rt = wg >> 3;
    int ct = wg & 7;
    const int kbmax = (*hflag) ? 16 : 8;

    f32x4 acc[4][4];
    #pragma unroll
    for (int mi = 0; mi < 4; ++mi)
        #pragma unroll
        for (int nj = 0; nj < 4; ++nj)
            acc[mi][nj] = (f32x4)0.0f;

    const size_t aoff = ((size_t)(rt * 4) * 16) * 512 + lane * 8;
    const size_t boff = ((size_t)(ct * 4) * 16) * 512 + lane * 8;

    for (int kb = 0; kb < kbmax; ++kb) {
        bf16x8 a[4], b[4];
        #pragma unroll
        for (int mi = 0; mi < 4; ++mi)
            a[mi] = *reinterpret_cast<const bf16x8*>(Abf + aoff + (size_t)(mi * 16 + kb) * 512);
        #pragma unroll
        for (int nj = 0; nj < 4; ++nj)
            b[nj] = *reinterpret_cast<const bf16x8*>(Wbf + boff + (size_t)(nj * 16 + kb) * 512);
        #pragma unroll
        for (int mi = 0; mi < 4; ++mi)
            #pragma unroll
            for (int nj = 0; nj < 4; ++nj)
                acc[mi][nj] = __builtin_amdgcn_mfma_f32_16x16x32_bf16(
                                  a[mi], b[nj], acc[mi][nj], 0, 0, 0);
    }

    const int r0 = rt * 64, c0 = ct * 64;
    #pragma unroll
    for (int mi = 0; mi < 4; ++mi) {
        #pragma unroll
        for (int q = 0; q < 4; ++q) {
            int r = r0 + mi * 16 + (lane >> 4) * 4 + q;
            if (r < n) {
                #pragma unroll
                for (int nj = 0; nj < 4; ++nj) {
                    int cc = c0 + nj * 16 + (lane & 15);
                    gates[(size_t)r * 512 + cc] = f2bf(acc[mi][nj][q]);
                }
            }
        }
    }
}

// ---- Kernel 10: LSTM gate combine, vectorized (8 cols / thread) ----
__global__ __launch_bounds__(256) void k_combine(
    const unsigned short* __restrict__ gates, const float* __restrict__ c,
    const float* __restrict__ b, const float* __restrict__ wc,
    float* __restrict__ out, int n) {

    int t = blockIdx.x * 256 + threadIdx.x;
    if (t >= n * 16) return;
    int row = t >> 4, col0 = (t & 15) * 8;

    const unsigned short* gr = gates + (size_t)row * 512;
    uint4 gu[4];
    #pragma unroll
    for (int g = 0; g < 4; ++g)
        gu[g] = *reinterpret_cast<const uint4*>(gr + g * FD + col0);

    float4 cva = *reinterpret_cast<const float4*>(c + (size_t)row * FD + col0);
    float4 cvb = *reinterpret_cast<const float4*>(c + (size_t)row * FD + col0 + 4);
    float cvv[8] = {cva.x, cva.y, cva.z, cva.w, cvb.x, cvb.y, cvb.z, cvb.w};

    float bv[4][8], wv[3][8];
    #pragma unroll
    for (int g = 0; g < 4; ++g) {
        float4 p0 = *reinterpret_cast<const float4*>(b + g * FD + col0);
        float4 p1 = *reinterpret_cast<const float4*>(b + g * FD + col0 + 4);
        bv[g][0]=p0.x; bv[g][1]=p0.y; bv[g][2]=p0.z; bv[g][3]=p0.w;
        bv[g][4]=p1.x; bv[g][5]=p1.y; bv[g][6]=p1.z; bv[g][7]=p1.w;
    }
    #pragma unroll
    for (int g = 0; g < 3; ++g) {
        float4 p0 = *reinterpret_cast<const float4*>(wc + g * FD + col0);
        float4 p1 = *reinterpret_cast<const float4*>(wc + g * FD + col0 + 4);
        wv[g][0]=p0.x; wv[g][1]=p0.y; wv[g][2]=p0.z; wv[g][3]=p0.w;
        wv[g][4]=p1.x; wv[g][5]=p1.y; wv[g][6]=p1.z; wv[g][7]=p1.w;
    }

    const unsigned int* g0p = &gu[0].x;
    const unsigned int* g1p = &gu[1].x;
    const unsigned int* g2p = &gu[2].x;
    const unsigned int* g3p = &gu[3].x;

    float ho[8], co[8];
    #pragma unroll
    for (int j = 0; j < 8; ++j) {
        float gi_ = ((j & 1) ? bfhi(g0p[j >> 1]) : bflo(g0p[j >> 1])) + wv[0][j] * cvv[j] + bv[0][j];
        float gf_ = ((j & 1) ? bfhi(g1p[j >> 1]) : bflo(g1p[j >> 1])) + wv[1][j] * cvv[j] + bv[1][j];
        float gg_ = ((j & 1) ? bfhi(g2p[j >> 1]) : bflo(g2p[j >> 1])) + bv[2][j];
        float iv = sigmoidf_(gi_);
        float fv = sigmoidf_(gf_);
        float cn = fv * cvv[j] + iv * tanhf(gg_);
        float go_ = ((j & 1) ? bfhi(g3p[j >> 1]) : bflo(g3p[j >> 1])) + wv[2][j] * cn + bv[3][j];
        ho[j] = sigmoidf_(go_) * tanhf(cn);
        co[j] = cn;
    }

    size_t NH = (size_t)n * FD;
    size_t o0 = (size_t)row * FD + col0;
    float4* p;
    p = reinterpret_cast<float4*>(out + o0);
    p[0] = make_float4(ho[0], ho[1], ho[2], ho[3]);
    p[1] = make_float4(ho[4], ho[5], ho[6], ho[7]);
    p = reinterpret_cast<float4*>(out + NH + o0);
    p[0] = make_float4(ho[0], ho[1], ho[2], ho[3]);
    p[1] = make_float4(ho[4], ho[5], ho[6], ho[7]);
    p = reinterpret_cast<float4*>(out + 2 * NH + o0);
    p[0] = make_float4(co[0], co[1], co[2], co[3]);
    p[1] = make_float4(co[4], co[5], co[6], co[7]);
}

extern "C" void kernel_launch(void* const* d_in, const int* in_sizes, int n_in,
                              void* d_out, int out_size, void* d_ws, size_t ws_size,
                              hipStream_t stream) {
    const float* x   = (const float*)d_in[0];
    const float* ew  = (const float*)d_in[1];
    const float* h   = (const float*)d_in[2];
    const float* c   = (const float*)d_in[3];
    const float* Wx  = (const float*)d_in[4];
    const float* Wh  = (const float*)d_in[5];
    const float* b   = (const float*)d_in[6];
    const float* wc  = (const float*)d_in[7];
    const int*   src = (const int*)d_in[8];
    const int*   dst = (const int*)d_in[9];

    const int n = in_sizes[0] / FD;   // 20000
    const int E = in_sizes[1];        // 640000

    const int Mpad = (n + 63) & ~63;
    const int ech  = (E + NB - 1) / NB;           // 5000
    const int rsh  = (n + NRH - 1) / NRH;         // 10000 (<= RSH_MAX)
    const int n16  = n * 16;
    const int nfp  = (n16 + 255) / 256;           // cvt block count

    // ---- workspace layout ----
    float* dis      = (float*)d_ws;                        // n
    int*   cnt      = (int*)(dis + n);                     // n
    int*   off      = cnt + n;                             // n+4
    int*   hflag    = off + n + 4;                         // 4
    int*   flagpart = hflag + 4;                           // nfp (pad 1280)
    int2*  epk      = (int2*)(flagpart + 1280);            // E
    unsigned int* xw = (unsigned int*)(epk + E);           // n*64 uints
    unsigned int* hw = xw + (size_t)n * 64;                // n*64
    unsigned short* gates = (unsigned short*)(hw + (size_t)n * 64);  // n*512
    unsigned short* Abf   = gates + (size_t)n * 512;       // Mpad*512
    unsigned short* Wbf   = Abf + (size_t)Mpad * 512;      // 512*512
    int*   curb     = (int*)(Wbf + 512 * 512);             // NB*n

    // aliases into gates (hist outputs die before gemm writes gates):
    float*          deg_priv = (float*)gates;                                // NB*n f32
    unsigned short* cnt_priv = (unsigned short*)(deg_priv + (size_t)NB * n); // NB*n u16

    k_cvt<<<nfp, 256, 0, stream>>>(x, h, xw, hw, Abf, flagpart, n16);
    k_hist_lds<<<NRH * NB, 512, 0, stream>>>(ew, src, dst, deg_priv, cnt_priv, E, n, ech, rsh);
    k_prep<<<(n + 255) / 256, 256, 0, stream>>>(deg_priv, cnt_priv, dis, cnt, n);
    k_scan<<<1, 1024, 0, stream>>>(cnt, off, flagpart, hflag, n, nfp);
    k_colscan<<<(n + 255) / 256, 256, 0, stream>>>(cnt_priv, off, curb, n);
    k_fill_lds<<<NB, 512, 0, stream>>>(ew, src, dst, dis, curb, epk, E, n, ech);
    k_gather_bf<<<(n + 3) / 4, 256, 0, stream>>>(xw, hw, off, epk, hflag, Abf, n);
    k_pack_w<<<512 / 4, 256, 0, stream>>>(Wx, Wh, Wbf);

    const int nwaves = (Mpad / 64) * 8;
    k_gemm_mfma<<<nwaves / 4, 256, 0, stream>>>(Abf, Wbf, hflag, gates, n);
    k_combine<<<(n16 + 255) / 256, 256, 0, stream>>>(gates, c, b, wc, (float*)d_out, n);
}